// Round 1
// baseline (2121.198 us; speedup 1.0000x reference)
//
#include <hip/hip_runtime.h>
#include <cmath>

#define NN   20000              // nodes
#define NE   320000             // raw edges
#define EE   (NE + NN)          // edges incl. self-loops
#define NG   64                 // graphs
#define NH   4                  // heads
#define NC   64                 // channels/head
#define HIDD 256                // NH*NC
#define IND  128                // input feature dim
#define LATD 64                 // latent dim
#define NEGS 0.2f
#define BNEPS 1e-5f

// ---------- helpers ----------
__device__ inline void atomicMaxF(float* a, float v) {
    // works because positive floats order as ints, negative floats reverse-order as uints
    if (v >= 0.f) atomicMax((int*)a, __float_as_int(v));
    else          atomicMin((unsigned int*)a, __float_as_uint(v));
}

__device__ inline int lower_bound_i(const int* __restrict__ b, int n, int key) {
    int lo = 0, hi = n;
    while (lo < hi) { int mid = (lo + hi) >> 1; if (b[mid] < key) lo = mid + 1; else hi = mid; }
    return lo;
}

__global__ void k_fill(float* __restrict__ p, int n, float v) {
    int i = blockIdx.x * blockDim.x + threadIdx.x;
    if (i < n) p[i] = v;
}

// ---------- xp = h @ W   (one block per node row, one thread per out column) ----------
__global__ void k_linear(const float* __restrict__ h, const float* __restrict__ W,
                         int K, float* __restrict__ xp) {
    int n = blockIdx.x;
    int col = threadIdx.x;                  // 256
    const float* hr = h + (size_t)n * K;
    float acc = 0.f;
    for (int k = 0; k < K; ++k) acc = fmaf(hr[k], W[k * HIDD + col], acc);
    xp[(size_t)n * HIDD + col] = acc;
}

// ---------- per-node attention scalars ----------
__global__ void k_att(const float* __restrict__ xp, const float* __restrict__ a_src,
                      const float* __restrict__ a_dst,
                      float* __restrict__ al_s, float* __restrict__ al_d) {
    int idx = blockIdx.x * blockDim.x + threadIdx.x;   // N*H
    if (idx >= NN * NH) return;
    int n = idx / NH, hh = idx % NH;
    const float* row = xp + (size_t)n * HIDD + hh * NC;
    float s = 0.f, d = 0.f;
    for (int c = 0; c < NC; ++c) {
        float v = row[c];
        s = fmaf(v, a_src[hh * NC + c], s);
        d = fmaf(v, a_dst[hh * NC + c], d);
    }
    al_s[idx] = s; al_d[idx] = d;
}

// ---------- edge logits + segment max over dst ----------
__global__ void k_edge_max(const int* __restrict__ ei, const float* __restrict__ al_s,
                           const float* __restrict__ al_d,
                           float* __restrict__ ebuf, float* __restrict__ emax) {
    int e = blockIdx.x * blockDim.x + threadIdx.x;
    if (e >= EE) return;
    int s, d;
    if (e < NE) { s = ei[e]; d = ei[NE + e]; } else { s = e - NE; d = s; }
    for (int hh = 0; hh < NH; ++hh) {
        float v = al_s[s * NH + hh] + al_d[d * NH + hh];
        v = v > 0.f ? v : NEGS * v;          // leaky relu
        ebuf[e * NH + hh] = v;
        atomicMaxF(&emax[d * NH + hh], v);
    }
}

// ---------- exp(e - max) + segment sum (denominator); ebuf updated in place ----------
__global__ void k_edge_exp(const int* __restrict__ ei, float* __restrict__ ebuf,
                           const float* __restrict__ emax, float* __restrict__ denom) {
    int idx = blockIdx.x * blockDim.x + threadIdx.x;   // EE*NH
    if (idx >= EE * NH) return;
    int e = idx >> 2, hh = idx & 3;
    int d = (e < NE) ? ei[NE + e] : (e - NE);
    float v = expf(ebuf[idx] - emax[d * NH + hh]);
    ebuf[idx] = v;
    atomicAdd(&denom[d * NH + hh], v);
}

// ---------- weighted scatter-add of source features ----------
__global__ void k_scatter(const int* __restrict__ ei, const float* __restrict__ xp,
                          const float* __restrict__ ebuf, const float* __restrict__ denom,
                          float* __restrict__ acc) {
    int e = blockIdx.x;                     // EE blocks
    int t = threadIdx.x;                    // 256
    int s, d;
    if (e < NE) { s = ei[e]; d = ei[NE + e]; } else { s = e - NE; d = s; }
    int hh = t >> 6;
    float alpha = ebuf[e * NH + hh] / (denom[d * NH + hh] + 1e-16f);
    atomicAdd(&acc[(size_t)d * HIDD + t], xp[(size_t)s * HIDD + t] * alpha);
}

// ---------- bias + BN(eval) + ReLU ----------
__global__ void k_bnrelu(const float* __restrict__ acc, const float* __restrict__ bias,
                         const float* __restrict__ g, const float* __restrict__ b,
                         const float* __restrict__ m, const float* __restrict__ v,
                         float* __restrict__ h) {
    int idx = blockIdx.x * blockDim.x + threadIdx.x;   // NN*HIDD
    if (idx >= NN * HIDD) return;
    int col = idx & (HIDD - 1);
    float val = acc[idx] + bias[col];
    val = (val - m[col]) * rsqrtf(v[col] + BNEPS) * g[col] + b[col];
    h[idx] = val > 0.f ? val : 0.f;
}

// ---------- mean-free segment_sum pooling over sorted batch ----------
__global__ void k_pool(const float* __restrict__ h, const int* __restrict__ batch,
                       float* __restrict__ pooled) {
    int g = blockIdx.x;                     // NG blocks
    int col = threadIdx.x;                  // 256
    int lo = lower_bound_i(batch, NN, g);
    int hi = lower_bound_i(batch, NN, g + 1);
    float acc = 0.f;
    for (int n = lo; n < hi; ++n) acc += h[(size_t)n * HIDD + col];
    pooled[g * HIDD + col] = acc;
}

// ---------- final BN + FC ----------
__global__ void k_final(const float* __restrict__ pooled, const float* __restrict__ lg,
                        const float* __restrict__ lb, const float* __restrict__ lm,
                        const float* __restrict__ lv, const float* __restrict__ fcW,
                        const float* __restrict__ fcb, float* __restrict__ out) {
    int g = blockIdx.x;                     // NG blocks
    int j = threadIdx.x;                    // 64
    float acc = 0.f;
    for (int k = 0; k < HIDD; ++k) {
        float v = (pooled[g * HIDD + k] - lm[k]) * rsqrtf(lv[k] + BNEPS) * lg[k] + lb[k];
        acc = fmaf(v, fcW[k * LATD + j], acc);
    }
    out[g * LATD + j] = acc + fcb[j];
}

extern "C" void kernel_launch(void* const* d_in, const int* in_sizes, int n_in,
                              void* d_out, int out_size, void* d_ws, size_t ws_size,
                              hipStream_t stream) {
    const float* x     = (const float*)d_in[0];
    const int*   ei    = (const int*)d_in[1];
    const int*   batch = (const int*)d_in[2];
    const float* W0    = (const float*)d_in[3];
    const float* Wr    = (const float*)d_in[4];
    const float* asrc  = (const float*)d_in[5];
    const float* adst  = (const float*)d_in[6];
    const float* bconv = (const float*)d_in[7];
    const float* bng   = (const float*)d_in[8];
    const float* bnb   = (const float*)d_in[9];
    const float* bnm   = (const float*)d_in[10];
    const float* bnv   = (const float*)d_in[11];
    const float* lg    = (const float*)d_in[12];
    const float* lb    = (const float*)d_in[13];
    const float* lm    = (const float*)d_in[14];
    const float* lv    = (const float*)d_in[15];
    const float* fcW   = (const float*)d_in[16];
    const float* fcb   = (const float*)d_in[17];
    float* out = (float*)d_out;

    // workspace carve-up (256B-aligned)
    char* w = (char*)d_ws;
    size_t off = 0;
    auto alloc = [&](size_t nf) {
        float* p = (float*)(w + off);
        off += ((nf * sizeof(float) + 255) / 256) * 256;
        return p;
    };
    float* xp    = alloc((size_t)NN * HIDD);   // transformed features
    float* hbuf  = alloc((size_t)NN * HIDD);   // layer activations
    float* acc   = alloc((size_t)NN * HIDD);   // aggregation accumulator
    float* ebuf  = alloc((size_t)EE * NH);     // edge logits -> exp values
    float* al_s  = alloc((size_t)NN * NH);
    float* al_d  = alloc((size_t)NN * NH);
    float* emax  = alloc((size_t)NN * NH);
    float* denom = alloc((size_t)NN * NH);
    float* pooled= alloc((size_t)NG * HIDD);

    for (int layer = 0; layer < 3; ++layer) {
        const float* hin = (layer == 0) ? x : hbuf;
        const float* W   = (layer == 0) ? W0 : (Wr + (size_t)(layer - 1) * HIDD * HIDD);
        int K            = (layer == 0) ? IND : HIDD;

        hipLaunchKernelGGL(k_linear, dim3(NN), dim3(HIDD), 0, stream, hin, W, K, xp);
        hipLaunchKernelGGL(k_att, dim3((NN * NH + 255) / 256), dim3(256), 0, stream,
                           xp, asrc + layer * NH * NC, adst + layer * NH * NC, al_s, al_d);
        hipLaunchKernelGGL(k_fill, dim3((NN * NH + 255) / 256), dim3(256), 0, stream,
                           emax, NN * NH, -INFINITY);
        hipMemsetAsync(denom, 0, (size_t)NN * NH * sizeof(float), stream);
        hipMemsetAsync(acc, 0, (size_t)NN * HIDD * sizeof(float), stream);
        hipLaunchKernelGGL(k_edge_max, dim3((EE + 255) / 256), dim3(256), 0, stream,
                           ei, al_s, al_d, ebuf, emax);
        hipLaunchKernelGGL(k_edge_exp, dim3((EE * NH + 255) / 256), dim3(256), 0, stream,
                           ei, ebuf, emax, denom);
        hipLaunchKernelGGL(k_scatter, dim3(EE), dim3(HIDD), 0, stream,
                           ei, xp, ebuf, denom, acc);
        hipLaunchKernelGGL(k_bnrelu, dim3((NN * HIDD + 255) / 256), dim3(256), 0, stream,
                           acc, bconv + layer * HIDD, bng + layer * HIDD, bnb + layer * HIDD,
                           bnm + layer * HIDD, bnv + layer * HIDD, hbuf);
    }

    hipLaunchKernelGGL(k_pool, dim3(NG), dim3(HIDD), 0, stream, hbuf, batch, pooled);
    hipLaunchKernelGGL(k_final, dim3(NG), dim3(LATD), 0, stream,
                       pooled, lg, lb, lm, lv, fcW, fcb, out);
}

// Round 2
// 1328.364 us; speedup vs baseline: 1.5968x; 1.5968x over previous
//
#include <hip/hip_runtime.h>
#include <hip/hip_bf16.h>
#include <cmath>

#define NN   20000              // nodes
#define NE   320000             // raw edges
#define EE   (NE + NN)          // edges incl. self-loops
#define NG   64                 // graphs
#define NH   4                  // heads
#define NC   64                 // channels/head
#define HIDD 256                // NH*NC
#define IND  128                // input feature dim
#define LATD 64                 // latent dim
#define NEGS 0.2f
#define BNEPS 1e-5f
#define MPAD 20096              // 157 * 128 (GEMM M padding)

// GEMM tile
#define BM 128
#define BN 64
#define BK 64

typedef __attribute__((ext_vector_type(8))) short short8;
typedef __attribute__((ext_vector_type(4))) float f32x4;

// ---------- helpers ----------
__device__ inline void atomicMaxF(float* a, float v) {
    if (v >= 0.f) atomicMax((int*)a, __float_as_int(v));
    else          atomicMin((unsigned int*)a, __float_as_uint(v));
}

__device__ inline int lower_bound_i(const int* __restrict__ b, int n, int key) {
    int lo = 0, hi = n;
    while (lo < hi) { int mid = (lo + hi) >> 1; if (b[mid] < key) lo = mid + 1; else hi = mid; }
    return lo;
}

__global__ void k_fill(float* __restrict__ p, int n, float v) {
    int i = blockIdx.x * blockDim.x + threadIdx.x;
    if (i < n) p[i] = v;
}

// ---------- fp32 -> bf16 cast of x ----------
__global__ void k_cast_x(const float* __restrict__ x, __hip_bfloat16* __restrict__ hbx) {
    int i = blockIdx.x * blockDim.x + threadIdx.x;     // over NN*IND/4
    if (i >= NN * IND / 4) return;
    float4 v = ((const float4*)x)[i];
    union { __hip_bfloat16 b[4]; ushort4 u; } cv;
    cv.b[0] = __float2bfloat16(v.x); cv.b[1] = __float2bfloat16(v.y);
    cv.b[2] = __float2bfloat16(v.z); cv.b[3] = __float2bfloat16(v.w);
    ((ushort4*)hbx)[i] = cv.u;
}

// ---------- W[K][256] -> Wt[256][K] bf16 ----------
__global__ void k_cast_wt(const float* __restrict__ W, int K, __hip_bfloat16* __restrict__ Wt) {
    int k = blockIdx.x;          // K blocks
    int n = threadIdx.x;         // 256
    Wt[(size_t)n * K + k] = __float2bfloat16(W[(size_t)k * HIDD + n]);
}

// ---------- MFMA GEMM: C[MPAD][256] = A[MPAD][K] @ Bt[256][K]^T ----------
__global__ __launch_bounds__(256) void k_gemm(const short* __restrict__ A,
                                              const short* __restrict__ Bt,
                                              int K, float* __restrict__ C) {
    __shared__ char As[BM * BK * 2];   // 16 KB, XOR-swizzled
    __shared__ char Bs[BN * BK * 2];   // 8 KB
    int tid = threadIdx.x;
    int lane = tid & 63;
    int wid = tid >> 6;
    int wm = wid >> 1, wn = wid & 1;               // 2x2 wave grid
    int bm0 = blockIdx.x * BM, bn0 = blockIdx.y * BN;
    int r16 = lane & 15, kg = lane >> 4;

    f32x4 acc[4][2];
    #pragma unroll
    for (int m = 0; m < 4; ++m)
        #pragma unroll
        for (int n = 0; n < 2; ++n) acc[m][n] = (f32x4){0.f, 0.f, 0.f, 0.f};

    for (int k0 = 0; k0 < K; k0 += BK) {
        __syncthreads();
        // stage A: 128 rows x 64 bf16; 4 passes of 256 thr x 16B
        #pragma unroll
        for (int p = 0; p < 4; ++p) {
            int row = p * 32 + (tid >> 3);
            int cg  = tid & 7;
            uint4 v = *(const uint4*)(A + (size_t)(bm0 + row) * K + k0 + cg * 8);
            *(uint4*)(As + row * 128 + ((cg * 16) ^ ((row & 7) << 4))) = v;
        }
        // stage B: 64 rows x 64 bf16; 2 passes
        #pragma unroll
        for (int p = 0; p < 2; ++p) {
            int row = p * 32 + (tid >> 3);
            int cg  = tid & 7;
            uint4 v = *(const uint4*)(Bt + (size_t)(bn0 + row) * K + k0 + cg * 8);
            *(uint4*)(Bs + row * 128 + ((cg * 16) ^ ((row & 7) << 4))) = v;
        }
        __syncthreads();
        #pragma unroll
        for (int kk = 0; kk < 2; ++kk) {
            short8 af[4], bfr[2];
            int kb = (kk * 32 + kg * 8) * 2;
            #pragma unroll
            for (int m = 0; m < 4; ++m) {
                int row = wm * 64 + m * 16 + r16;
                af[m] = *(const short8*)(As + row * 128 + (kb ^ ((row & 7) << 4)));
            }
            #pragma unroll
            for (int n = 0; n < 2; ++n) {
                int row = wn * 32 + n * 16 + r16;
                bfr[n] = *(const short8*)(Bs + row * 128 + (kb ^ ((row & 7) << 4)));
            }
            #pragma unroll
            for (int m = 0; m < 4; ++m)
                #pragma unroll
                for (int n = 0; n < 2; ++n)
                    acc[m][n] = __builtin_amdgcn_mfma_f32_16x16x32_bf16(af[m], bfr[n], acc[m][n], 0, 0, 0);
        }
    }
    // epilogue: D row = kg*4 + r, col = r16 within each 16x16 fragment
    #pragma unroll
    for (int m = 0; m < 4; ++m) {
        int row = bm0 + wm * 64 + m * 16 + kg * 4;
        #pragma unroll
        for (int n = 0; n < 2; ++n) {
            int col = bn0 + wn * 32 + n * 16 + r16;
            #pragma unroll
            for (int r = 0; r < 4; ++r)
                C[(size_t)(row + r) * HIDD + col] = acc[m][n][r];
        }
    }
}

// ---------- per-node attention scalars ----------
__global__ void k_att(const float* __restrict__ xp, const float* __restrict__ a_src,
                      const float* __restrict__ a_dst,
                      float* __restrict__ al_s, float* __restrict__ al_d) {
    int idx = blockIdx.x * blockDim.x + threadIdx.x;   // N*H
    if (idx >= NN * NH) return;
    int n = idx / NH, hh = idx % NH;
    const float* row = xp + (size_t)n * HIDD + hh * NC;
    float s = 0.f, d = 0.f;
    for (int c = 0; c < NC; ++c) {
        float v = row[c];
        s = fmaf(v, a_src[hh * NC + c], s);
        d = fmaf(v, a_dst[hh * NC + c], d);
    }
    al_s[idx] = s; al_d[idx] = d;
}

// ---------- edge logits + segment max over dst ----------
__global__ void k_edge_max(const int* __restrict__ ei, const float* __restrict__ al_s,
                           const float* __restrict__ al_d,
                           float* __restrict__ ebuf, float* __restrict__ emax) {
    int e = blockIdx.x * blockDim.x + threadIdx.x;
    if (e >= EE) return;
    int s, d;
    if (e < NE) { s = ei[e]; d = ei[NE + e]; } else { s = e - NE; d = s; }
    for (int hh = 0; hh < NH; ++hh) {
        float v = al_s[s * NH + hh] + al_d[d * NH + hh];
        v = v > 0.f ? v : NEGS * v;          // leaky relu
        ebuf[e * NH + hh] = v;
        atomicMaxF(&emax[d * NH + hh], v);
    }
}

// ---------- exp(e - max) + segment sum ----------
__global__ void k_edge_exp(const int* __restrict__ ei, float* __restrict__ ebuf,
                           const float* __restrict__ emax, float* __restrict__ denom) {
    int idx = blockIdx.x * blockDim.x + threadIdx.x;   // EE*NH
    if (idx >= EE * NH) return;
    int e = idx >> 2, hh = idx & 3;
    int d = (e < NE) ? ei[NE + e] : (e - NE);
    float v = expf(ebuf[idx] - emax[d * NH + hh]);
    ebuf[idx] = v;
    atomicAdd(&denom[d * NH + hh], v);
}

// ---------- weighted scatter-add of source features ----------
__global__ void k_scatter(const int* __restrict__ ei, const float* __restrict__ xp,
                          const float* __restrict__ ebuf, const float* __restrict__ denom,
                          float* __restrict__ acc) {
    int e = blockIdx.x;                     // EE blocks
    int t = threadIdx.x;                    // 256
    int s, d;
    if (e < NE) { s = ei[e]; d = ei[NE + e]; } else { s = e - NE; d = s; }
    int hh = t >> 6;
    float alpha = ebuf[e * NH + hh] / (denom[d * NH + hh] + 1e-16f);
    atomicAdd(&acc[(size_t)d * HIDD + t], xp[(size_t)s * HIDD + t] * alpha);
}

// ---------- bias + BN(eval) + ReLU (+ bf16 copy for next GEMM) ----------
__global__ void k_bnrelu(const float* __restrict__ acc, const float* __restrict__ bias,
                         const float* __restrict__ g, const float* __restrict__ b,
                         const float* __restrict__ m, const float* __restrict__ v,
                         float* __restrict__ h, __hip_bfloat16* __restrict__ hb) {
    int idx = blockIdx.x * blockDim.x + threadIdx.x;   // NN*HIDD
    if (idx >= NN * HIDD) return;
    int col = idx & (HIDD - 1);
    float val = acc[idx] + bias[col];
    val = (val - m[col]) * rsqrtf(v[col] + BNEPS) * g[col] + b[col];
    val = val > 0.f ? val : 0.f;
    h[idx] = val;
    hb[idx] = __float2bfloat16(val);
}

// ---------- pooling over sorted batch ----------
__global__ void k_pool(const float* __restrict__ h, const int* __restrict__ batch,
                       float* __restrict__ pooled) {
    int g = blockIdx.x;                     // NG blocks
    int col = threadIdx.x;                  // 256
    int lo = lower_bound_i(batch, NN, g);
    int hi = lower_bound_i(batch, NN, g + 1);
    float acc = 0.f;
    for (int n = lo; n < hi; ++n) acc += h[(size_t)n * HIDD + col];
    pooled[g * HIDD + col] = acc;
}

// ---------- final BN + FC ----------
__global__ void k_final(const float* __restrict__ pooled, const float* __restrict__ lg,
                        const float* __restrict__ lb, const float* __restrict__ lm,
                        const float* __restrict__ lv, const float* __restrict__ fcW,
                        const float* __restrict__ fcb, float* __restrict__ out) {
    int g = blockIdx.x;                     // NG blocks
    int j = threadIdx.x;                    // 64
    float acc = 0.f;
    for (int k = 0; k < HIDD; ++k) {
        float v = (pooled[g * HIDD + k] - lm[k]) * rsqrtf(lv[k] + BNEPS) * lg[k] + lb[k];
        acc = fmaf(v, fcW[k * LATD + j], acc);
    }
    out[g * LATD + j] = acc + fcb[j];
}

extern "C" void kernel_launch(void* const* d_in, const int* in_sizes, int n_in,
                              void* d_out, int out_size, void* d_ws, size_t ws_size,
                              hipStream_t stream) {
    const float* x     = (const float*)d_in[0];
    const int*   ei    = (const int*)d_in[1];
    const int*   batch = (const int*)d_in[2];
    const float* W0    = (const float*)d_in[3];
    const float* Wr    = (const float*)d_in[4];
    const float* asrc  = (const float*)d_in[5];
    const float* adst  = (const float*)d_in[6];
    const float* bconv = (const float*)d_in[7];
    const float* bng   = (const float*)d_in[8];
    const float* bnb   = (const float*)d_in[9];
    const float* bnm   = (const float*)d_in[10];
    const float* bnv   = (const float*)d_in[11];
    const float* lg    = (const float*)d_in[12];
    const float* lb    = (const float*)d_in[13];
    const float* lm    = (const float*)d_in[14];
    const float* lv    = (const float*)d_in[15];
    const float* fcW   = (const float*)d_in[16];
    const float* fcb   = (const float*)d_in[17];
    float* out = (float*)d_out;

    char* w = (char*)d_ws;
    size_t off = 0;
    auto alloc = [&](size_t bytes) {
        char* p = w + off;
        off += (bytes + 255) / 256 * 256;
        return p;
    };
    float* xp    = (float*)alloc((size_t)MPAD * HIDD * 4);  // transformed features (padded)
    float* hbuf  = (float*)alloc((size_t)NN * HIDD * 4);    // layer activations fp32
    float* acc   = (float*)alloc((size_t)NN * HIDD * 4);    // aggregation accumulator
    float* ebuf  = (float*)alloc((size_t)EE * NH * 4);      // edge logits -> exp
    float* al_s  = (float*)alloc((size_t)NN * NH * 4);
    float* al_d  = (float*)alloc((size_t)NN * NH * 4);
    float* emax  = (float*)alloc((size_t)NN * NH * 4);
    float* denom = (float*)alloc((size_t)NN * NH * 4);
    float* pooled= (float*)alloc((size_t)NG * HIDD * 4);
    __hip_bfloat16* hbx = (__hip_bfloat16*)alloc((size_t)MPAD * IND * 2);   // bf16 x
    __hip_bfloat16* hb2 = (__hip_bfloat16*)alloc((size_t)MPAD * HIDD * 2);  // bf16 activations
    __hip_bfloat16* Wt  = (__hip_bfloat16*)alloc((size_t)HIDD * HIDD * 2);  // bf16 W^T

    hipLaunchKernelGGL(k_cast_x, dim3((NN * IND / 4 + 255) / 256), dim3(256), 0, stream, x, hbx);

    for (int layer = 0; layer < 3; ++layer) {
        const float* W = (layer == 0) ? W0 : (Wr + (size_t)(layer - 1) * HIDD * HIDD);
        int K          = (layer == 0) ? IND : HIDD;
        const __hip_bfloat16* Ab = (layer == 0) ? hbx : hb2;

        hipLaunchKernelGGL(k_cast_wt, dim3(K), dim3(HIDD), 0, stream, W, K, Wt);
        hipLaunchKernelGGL(k_gemm, dim3(MPAD / BM, HIDD / BN), dim3(256), 0, stream,
                           (const short*)Ab, (const short*)Wt, K, xp);
        hipLaunchKernelGGL(k_att, dim3((NN * NH + 255) / 256), dim3(256), 0, stream,
                           xp, asrc + layer * NH * NC, adst + layer * NH * NC, al_s, al_d);
        hipLaunchKernelGGL(k_fill, dim3((NN * NH + 255) / 256), dim3(256), 0, stream,
                           emax, NN * NH, -INFINITY);
        hipMemsetAsync(denom, 0, (size_t)NN * NH * sizeof(float), stream);
        hipMemsetAsync(acc, 0, (size_t)NN * HIDD * sizeof(float), stream);
        hipLaunchKernelGGL(k_edge_max, dim3((EE + 255) / 256), dim3(256), 0, stream,
                           ei, al_s, al_d, ebuf, emax);
        hipLaunchKernelGGL(k_edge_exp, dim3((EE * NH + 255) / 256), dim3(256), 0, stream,
                           ei, ebuf, emax, denom);
        hipLaunchKernelGGL(k_scatter, dim3(EE), dim3(HIDD), 0, stream,
                           ei, xp, ebuf, denom, acc);
        hipLaunchKernelGGL(k_bnrelu, dim3((NN * HIDD + 255) / 256), dim3(256), 0, stream,
                           acc, bconv + layer * HIDD, bng + layer * HIDD, bnb + layer * HIDD,
                           bnm + layer * HIDD, bnv + layer * HIDD, hbuf, hb2);
    }

    hipLaunchKernelGGL(k_pool, dim3(NG), dim3(HIDD), 0, stream, hbuf, batch, pooled);
    hipLaunchKernelGGL(k_final, dim3(NG), dim3(LATD), 0, stream,
                       pooled, lg, lb, lm, lv, fcW, fcb, out);
}

// Round 3
// 521.988 us; speedup vs baseline: 4.0637x; 2.5448x over previous
//
#include <hip/hip_runtime.h>
#include <hip/hip_bf16.h>
#include <cmath>

#define NN   20000              // nodes
#define NE   320000             // raw edges
#define EE   (NE + NN)          // edges incl. self-loops
#define NG   64                 // graphs
#define NH   4                  // heads
#define NC   64                 // channels/head
#define HIDD 256                // NH*NC
#define IND  128                // input feature dim
#define LATD 64                 // latent dim
#define NEGS 0.2f
#define BNEPS 1e-5f
#define MPAD 20096              // 157 * 128 (GEMM M padding)

// GEMM tile
#define BM 128
#define BN 64
#define BK 64

typedef __attribute__((ext_vector_type(8))) short short8;
typedef __attribute__((ext_vector_type(4))) float f32x4;

__device__ inline int lower_bound_i(const int* __restrict__ b, int n, int key) {
    int lo = 0, hi = n;
    while (lo < hi) { int mid = (lo + hi) >> 1; if (b[mid] < key) lo = mid + 1; else hi = mid; }
    return lo;
}

__device__ inline float sel4(float4 v, int h) {
    float r = v.x;
    r = (h == 1) ? v.y : r;
    r = (h == 2) ? v.z : r;
    r = (h == 3) ? v.w : r;
    return r;
}

// ---------- fp32 -> bf16 cast of x ----------
__global__ void k_cast_x(const float* __restrict__ x, __hip_bfloat16* __restrict__ hbx) {
    int i = blockIdx.x * blockDim.x + threadIdx.x;     // over NN*IND/4
    if (i >= NN * IND / 4) return;
    float4 v = ((const float4*)x)[i];
    union { __hip_bfloat16 b[4]; ushort4 u; } cv;
    cv.b[0] = __float2bfloat16(v.x); cv.b[1] = __float2bfloat16(v.y);
    cv.b[2] = __float2bfloat16(v.z); cv.b[3] = __float2bfloat16(v.w);
    ((ushort4*)hbx)[i] = cv.u;
}

// ---------- W[K][256] -> Wt[256][K] bf16 ----------
__global__ void k_cast_wt(const float* __restrict__ W, int K, __hip_bfloat16* __restrict__ Wt) {
    int k = blockIdx.x;          // K blocks
    int n = threadIdx.x;         // 256
    Wt[(size_t)n * K + k] = __float2bfloat16(W[(size_t)k * HIDD + n]);
}

// ---------- CSR build: histogram of dst ----------
__global__ void k_hist(const int* __restrict__ ei, int* __restrict__ deg) {
    int e = blockIdx.x * blockDim.x + threadIdx.x;
    if (e >= EE) return;
    int d = (e < NE) ? ei[NE + e] : (e - NE);
    atomicAdd(&deg[d], 1);
}

// ---------- CSR build: exclusive scan (1 block, 1024 threads) ----------
__global__ __launch_bounds__(1024) void k_scan(const int* __restrict__ deg,
                                               int* __restrict__ row_ptr,
                                               int* __restrict__ cursor) {
    __shared__ int tmp[1024];
    __shared__ int carry_s;
    int tid = threadIdx.x;
    if (tid == 0) carry_s = 0;
    __syncthreads();
    for (int base = 0; base < NN; base += 1024) {
        int i = base + tid;
        int v = (i < NN) ? deg[i] : 0;
        tmp[tid] = v;
        __syncthreads();
        for (int off = 1; off < 1024; off <<= 1) {
            int t = (tid >= off) ? tmp[tid - off] : 0;
            __syncthreads();
            tmp[tid] += t;
            __syncthreads();
        }
        int excl = carry_s + tmp[tid] - v;
        if (i < NN) { row_ptr[i] = excl; cursor[i] = excl; }
        __syncthreads();
        if (tid == 1023) carry_s += tmp[1023];
        __syncthreads();
    }
    if (tid == 0) row_ptr[NN] = carry_s;
}

// ---------- CSR build: scatter src into dst-sorted order ----------
__global__ void k_csr_scatter(const int* __restrict__ ei, int* __restrict__ cursor,
                              int* __restrict__ col_idx) {
    int e = blockIdx.x * blockDim.x + threadIdx.x;
    if (e >= EE) return;
    int s, d;
    if (e < NE) { s = ei[e]; d = ei[NE + e]; } else { s = d = e - NE; }
    int pos = atomicAdd(&cursor[d], 1);
    col_idx[pos] = s;
}

// ---------- MFMA GEMM: C[MPAD][256] = A[MPAD][K] @ Bt[256][K]^T ----------
__global__ __launch_bounds__(256) void k_gemm(const short* __restrict__ A,
                                              const short* __restrict__ Bt,
                                              int K, float* __restrict__ C) {
    __shared__ char As[BM * BK * 2];   // 16 KB, XOR-swizzled
    __shared__ char Bs[BN * BK * 2];   // 8 KB
    int tid = threadIdx.x;
    int lane = tid & 63;
    int wid = tid >> 6;
    int wm = wid >> 1, wn = wid & 1;               // 2x2 wave grid
    int bm0 = blockIdx.x * BM, bn0 = blockIdx.y * BN;
    int r16 = lane & 15, kg = lane >> 4;

    f32x4 acc[4][2];
    #pragma unroll
    for (int m = 0; m < 4; ++m)
        #pragma unroll
        for (int n = 0; n < 2; ++n) acc[m][n] = (f32x4){0.f, 0.f, 0.f, 0.f};

    for (int k0 = 0; k0 < K; k0 += BK) {
        __syncthreads();
        #pragma unroll
        for (int p = 0; p < 4; ++p) {
            int row = p * 32 + (tid >> 3);
            int cg  = tid & 7;
            uint4 v = *(const uint4*)(A + (size_t)(bm0 + row) * K + k0 + cg * 8);
            *(uint4*)(As + row * 128 + ((cg * 16) ^ ((row & 7) << 4))) = v;
        }
        #pragma unroll
        for (int p = 0; p < 2; ++p) {
            int row = p * 32 + (tid >> 3);
            int cg  = tid & 7;
            uint4 v = *(const uint4*)(Bt + (size_t)(bn0 + row) * K + k0 + cg * 8);
            *(uint4*)(Bs + row * 128 + ((cg * 16) ^ ((row & 7) << 4))) = v;
        }
        __syncthreads();
        #pragma unroll
        for (int kk = 0; kk < 2; ++kk) {
            short8 af[4], bfr[2];
            int kb = (kk * 32 + kg * 8) * 2;
            #pragma unroll
            for (int m = 0; m < 4; ++m) {
                int row = wm * 64 + m * 16 + r16;
                af[m] = *(const short8*)(As + row * 128 + (kb ^ ((row & 7) << 4)));
            }
            #pragma unroll
            for (int n = 0; n < 2; ++n) {
                int row = wn * 32 + n * 16 + r16;
                bfr[n] = *(const short8*)(Bs + row * 128 + (kb ^ ((row & 7) << 4)));
            }
            #pragma unroll
            for (int m = 0; m < 4; ++m)
                #pragma unroll
                for (int n = 0; n < 2; ++n)
                    acc[m][n] = __builtin_amdgcn_mfma_f32_16x16x32_bf16(af[m], bfr[n], acc[m][n], 0, 0, 0);
        }
    }
    #pragma unroll
    for (int m = 0; m < 4; ++m) {
        int row = bm0 + wm * 64 + m * 16 + kg * 4;
        #pragma unroll
        for (int n = 0; n < 2; ++n) {
            int col = bn0 + wn * 32 + n * 16 + r16;
            #pragma unroll
            for (int r = 0; r < 4; ++r)
                C[(size_t)(row + r) * HIDD + col] = acc[m][n][r];
        }
    }
}

// ---------- per-node attention scalars ----------
__global__ void k_att(const float* __restrict__ xp, const float* __restrict__ a_src,
                      const float* __restrict__ a_dst,
                      float* __restrict__ al_s, float* __restrict__ al_d) {
    int idx = blockIdx.x * blockDim.x + threadIdx.x;   // N*H
    if (idx >= NN * NH) return;
    int n = idx / NH, hh = idx % NH;
    const float* row = xp + (size_t)n * HIDD + hh * NC;
    float s = 0.f, d = 0.f;
    for (int c = 0; c < NC; ++c) {
        float v = row[c];
        s = fmaf(v, a_src[hh * NC + c], s);
        d = fmaf(v, a_dst[hh * NC + c], d);
    }
    al_s[idx] = s; al_d[idx] = d;
}

// ---------- fused edge-softmax + gather-aggregate + bias/BN/ReLU ----------
// one wave per destination node, 4 nodes per block
__global__ __launch_bounds__(256) void k_gat_agg(
        const int* __restrict__ row_ptr, const int* __restrict__ col_idx,
        const float* __restrict__ al_s, const float* __restrict__ al_d,
        const float* __restrict__ xp,
        const float* __restrict__ bias, const float* __restrict__ bg,
        const float* __restrict__ bb, const float* __restrict__ bm,
        const float* __restrict__ bv,
        float* __restrict__ h, __hip_bfloat16* __restrict__ hb) {
    int wid = threadIdx.x >> 6, lane = threadIdx.x & 63;
    int node = blockIdx.x * 4 + wid;
    if (node >= NN) return;
    int lo = row_ptr[node], hi = row_ptr[node + 1];
    int hsel = lane >> 4;                              // head of this lane's 4 columns
    float4 ad4 = ((const float4*)al_d)[node];
    float adh = sel4(ad4, hsel);

    // pass 1: online softmax max & denominator (per-lane scalar, own head)
    float mrun = -INFINITY, srun = 0.f;
    for (int e = lo; e < hi; ++e) {
        int sc = col_idx[e];
        float4 as4 = ((const float4*)al_s)[sc];
        float lg = sel4(as4, hsel) + adh;
        lg = lg > 0.f ? lg : NEGS * lg;
        float nm = fmaxf(mrun, lg);
        srun = srun * __expf(mrun - nm) + __expf(lg - nm);
        mrun = nm;
    }
    float inv = 1.f / (srun + 1e-16f);

    // pass 2: weighted gather-accumulate
    float4 acc = {0.f, 0.f, 0.f, 0.f};
    for (int e = lo; e < hi; ++e) {
        int sc = col_idx[e];
        float4 as4 = ((const float4*)al_s)[sc];
        float lg = sel4(as4, hsel) + adh;
        lg = lg > 0.f ? lg : NEGS * lg;
        float alpha = __expf(lg - mrun) * inv;
        float4 xv = ((const float4*)(xp + (size_t)sc * HIDD))[lane];
        acc.x = fmaf(alpha, xv.x, acc.x);
        acc.y = fmaf(alpha, xv.y, acc.y);
        acc.z = fmaf(alpha, xv.z, acc.z);
        acc.w = fmaf(alpha, xv.w, acc.w);
    }

    // epilogue: bias + BN(eval) + ReLU, store fp32 + bf16
    float4 bi = ((const float4*)bias)[lane];
    float4 gg = ((const float4*)bg)[lane];
    float4 be = ((const float4*)bb)[lane];
    float4 mn = ((const float4*)bm)[lane];
    float4 vr = ((const float4*)bv)[lane];
    float4 val;
    val.x = (acc.x + bi.x - mn.x) * rsqrtf(vr.x + BNEPS) * gg.x + be.x;
    val.y = (acc.y + bi.y - mn.y) * rsqrtf(vr.y + BNEPS) * gg.y + be.y;
    val.z = (acc.z + bi.z - mn.z) * rsqrtf(vr.z + BNEPS) * gg.z + be.z;
    val.w = (acc.w + bi.w - mn.w) * rsqrtf(vr.w + BNEPS) * gg.w + be.w;
    val.x = val.x > 0.f ? val.x : 0.f;
    val.y = val.y > 0.f ? val.y : 0.f;
    val.z = val.z > 0.f ? val.z : 0.f;
    val.w = val.w > 0.f ? val.w : 0.f;
    ((float4*)h)[(size_t)node * 64 + lane] = val;
    union { __hip_bfloat16 b[4]; ushort4 u; } cv;
    cv.b[0] = __float2bfloat16(val.x); cv.b[1] = __float2bfloat16(val.y);
    cv.b[2] = __float2bfloat16(val.z); cv.b[3] = __float2bfloat16(val.w);
    ((ushort4*)hb)[(size_t)node * 64 + lane] = cv.u;
}

// ---------- pooling over sorted batch ----------
__global__ void k_pool(const float* __restrict__ h, const int* __restrict__ batch,
                       float* __restrict__ pooled) {
    int g = blockIdx.x;                     // NG blocks
    int col = threadIdx.x;                  // 256
    int lo = lower_bound_i(batch, NN, g);
    int hi = lower_bound_i(batch, NN, g + 1);
    float acc = 0.f;
    for (int n = lo; n < hi; ++n) acc += h[(size_t)n * HIDD + col];
    pooled[g * HIDD + col] = acc;
}

// ---------- final BN + FC ----------
__global__ void k_final(const float* __restrict__ pooled, const float* __restrict__ lg,
                        const float* __restrict__ lb, const float* __restrict__ lm,
                        const float* __restrict__ lv, const float* __restrict__ fcW,
                        const float* __restrict__ fcb, float* __restrict__ out) {
    int g = blockIdx.x;                     // NG blocks
    int j = threadIdx.x;                    // 64
    float acc = 0.f;
    for (int k = 0; k < HIDD; ++k) {
        float v = (pooled[g * HIDD + k] - lm[k]) * rsqrtf(lv[k] + BNEPS) * lg[k] + lb[k];
        acc = fmaf(v, fcW[k * LATD + j], acc);
    }
    out[g * LATD + j] = acc + fcb[j];
}

extern "C" void kernel_launch(void* const* d_in, const int* in_sizes, int n_in,
                              void* d_out, int out_size, void* d_ws, size_t ws_size,
                              hipStream_t stream) {
    const float* x     = (const float*)d_in[0];
    const int*   ei    = (const int*)d_in[1];
    const int*   batch = (const int*)d_in[2];
    const float* W0    = (const float*)d_in[3];
    const float* Wr    = (const float*)d_in[4];
    const float* asrc  = (const float*)d_in[5];
    const float* adst  = (const float*)d_in[6];
    const float* bconv = (const float*)d_in[7];
    const float* bng   = (const float*)d_in[8];
    const float* bnb   = (const float*)d_in[9];
    const float* bnm   = (const float*)d_in[10];
    const float* bnv   = (const float*)d_in[11];
    const float* lg    = (const float*)d_in[12];
    const float* lb    = (const float*)d_in[13];
    const float* lm    = (const float*)d_in[14];
    const float* lv    = (const float*)d_in[15];
    const float* fcW   = (const float*)d_in[16];
    const float* fcb   = (const float*)d_in[17];
    float* out = (float*)d_out;

    char* w = (char*)d_ws;
    size_t off = 0;
    auto alloc = [&](size_t bytes) {
        char* p = w + off;
        off += (bytes + 255) / 256 * 256;
        return p;
    };
    float* xp    = (float*)alloc((size_t)MPAD * HIDD * 4);  // transformed features (padded)
    float* hbuf  = (float*)alloc((size_t)NN * HIDD * 4);    // layer activations fp32
    float* al_s  = (float*)alloc((size_t)NN * NH * 4);
    float* al_d  = (float*)alloc((size_t)NN * NH * 4);
    float* pooled= (float*)alloc((size_t)NG * HIDD * 4);
    __hip_bfloat16* hbx = (__hip_bfloat16*)alloc((size_t)MPAD * IND * 2);   // bf16 x
    __hip_bfloat16* hb2 = (__hip_bfloat16*)alloc((size_t)MPAD * HIDD * 2);  // bf16 activations
    __hip_bfloat16* Wt  = (__hip_bfloat16*)alloc((size_t)HIDD * HIDD * 2);  // bf16 W^T
    int* deg     = (int*)alloc((size_t)NN * 4);
    int* row_ptr = (int*)alloc((size_t)(NN + 1) * 4);
    int* cursor  = (int*)alloc((size_t)NN * 4);
    int* col_idx = (int*)alloc((size_t)EE * 4);

    // ---- CSR build (dst-sorted edges) ----
    hipMemsetAsync(deg, 0, (size_t)NN * sizeof(int), stream);
    hipLaunchKernelGGL(k_hist, dim3((EE + 255) / 256), dim3(256), 0, stream, ei, deg);
    hipLaunchKernelGGL(k_scan, dim3(1), dim3(1024), 0, stream, deg, row_ptr, cursor);
    hipLaunchKernelGGL(k_csr_scatter, dim3((EE + 255) / 256), dim3(256), 0, stream,
                       ei, cursor, col_idx);

    hipLaunchKernelGGL(k_cast_x, dim3((NN * IND / 4 + 255) / 256), dim3(256), 0, stream, x, hbx);

    for (int layer = 0; layer < 3; ++layer) {
        const float* W = (layer == 0) ? W0 : (Wr + (size_t)(layer - 1) * HIDD * HIDD);
        int K          = (layer == 0) ? IND : HIDD;
        const __hip_bfloat16* Ab = (layer == 0) ? hbx : hb2;

        hipLaunchKernelGGL(k_cast_wt, dim3(K), dim3(HIDD), 0, stream, W, K, Wt);
        hipLaunchKernelGGL(k_gemm, dim3(MPAD / BM, HIDD / BN), dim3(256), 0, stream,
                           (const short*)Ab, (const short*)Wt, K, xp);
        hipLaunchKernelGGL(k_att, dim3((NN * NH + 255) / 256), dim3(256), 0, stream,
                           xp, asrc + layer * NH * NC, adst + layer * NH * NC, al_s, al_d);
        hipLaunchKernelGGL(k_gat_agg, dim3((NN + 3) / 4), dim3(256), 0, stream,
                           row_ptr, col_idx, al_s, al_d, xp,
                           bconv + layer * HIDD, bng + layer * HIDD, bnb + layer * HIDD,
                           bnm + layer * HIDD, bnv + layer * HIDD, hbuf, hb2);
    }

    hipLaunchKernelGGL(k_pool, dim3(NG), dim3(HIDD), 0, stream, hbuf, batch, pooled);
    hipLaunchKernelGGL(k_final, dim3(NG), dim3(LATD), 0, stream,
                       pooled, lg, lb, lm, lv, fcW, fcb, out);
}

// Round 4
// 408.483 us; speedup vs baseline: 5.1929x; 1.2779x over previous
//
#include <hip/hip_runtime.h>
#include <hip/hip_bf16.h>
#include <cmath>

#define NN   20000              // nodes
#define NE   320000             // raw edges
#define EE   (NE + NN)          // edges incl. self-loops
#define NG   64                 // graphs
#define NH   4                  // heads
#define NC   64                 // channels/head
#define HIDD 256                // NH*NC
#define IND  128                // input feature dim
#define LATD 64                 // latent dim
#define NEGS 0.2f
#define BNEPS 1e-5f
#define MPAD 20096              // 157 * 128 (GEMM M padding)
#define PSPLIT 16               // pooling chunks per graph

// GEMM tile
#define BM 128
#define BN 64
#define BK 64

typedef __attribute__((ext_vector_type(8))) short short8;
typedef __attribute__((ext_vector_type(4))) float f32x4;

__device__ inline int lower_bound_i(const int* __restrict__ b, int n, int key) {
    int lo = 0, hi = n;
    while (lo < hi) { int mid = (lo + hi) >> 1; if (b[mid] < key) lo = mid + 1; else hi = mid; }
    return lo;
}

__device__ inline float sel4(float4 v, int h) {
    float r = v.x;
    r = (h == 1) ? v.y : r;
    r = (h == 2) ? v.z : r;
    r = (h == 3) ? v.w : r;
    return r;
}

__device__ inline float bf2f(unsigned short u) {
    return __uint_as_float(((unsigned int)u) << 16);
}

// ---------- fp32 -> bf16 cast of x ----------
__global__ void k_cast_x(const float* __restrict__ x, __hip_bfloat16* __restrict__ hbx) {
    int i = blockIdx.x * blockDim.x + threadIdx.x;     // over NN*IND/4
    if (i >= NN * IND / 4) return;
    float4 v = ((const float4*)x)[i];
    union { __hip_bfloat16 b[4]; ushort4 u; } cv;
    cv.b[0] = __float2bfloat16(v.x); cv.b[1] = __float2bfloat16(v.y);
    cv.b[2] = __float2bfloat16(v.z); cv.b[3] = __float2bfloat16(v.w);
    ((ushort4*)hbx)[i] = cv.u;
}

// ---------- W[K][256] -> Wt[256][K] bf16 ----------
__global__ void k_cast_wt(const float* __restrict__ W, int K, __hip_bfloat16* __restrict__ Wt) {
    int k = blockIdx.x;          // K blocks
    int n = threadIdx.x;         // 256
    Wt[(size_t)n * K + k] = __float2bfloat16(W[(size_t)k * HIDD + n]);
}

// ---------- CSR build: histogram of dst ----------
__global__ void k_hist(const int* __restrict__ ei, int* __restrict__ deg) {
    int e = blockIdx.x * blockDim.x + threadIdx.x;
    if (e >= EE) return;
    int d = (e < NE) ? ei[NE + e] : (e - NE);
    atomicAdd(&deg[d], 1);
}

// ---------- CSR build: chunked exclusive scan (1 block, 256 threads) ----------
#define SCHUNK ((NN + 255) / 256)
__global__ __launch_bounds__(256) void k_scan256(const int* __restrict__ deg,
                                                 int* __restrict__ row_ptr,
                                                 int* __restrict__ cursor) {
    __shared__ int part[256];
    int tid = threadIdx.x;
    int base = tid * SCHUNK;
    int cnt = NN - base; cnt = cnt < 0 ? 0 : (cnt > SCHUNK ? SCHUNK : cnt);
    int sum = 0;
    for (int j = 0; j < cnt; ++j) sum += deg[base + j];
    part[tid] = sum;
    __syncthreads();
    for (int off = 1; off < 256; off <<= 1) {
        int t = (tid >= off) ? part[tid - off] : 0;
        __syncthreads();
        part[tid] += t;
        __syncthreads();
    }
    int excl = part[tid] - sum;
    for (int j = 0; j < cnt; ++j) {
        row_ptr[base + j] = excl; cursor[base + j] = excl;
        excl += deg[base + j];
    }
    if (tid == 255) row_ptr[NN] = part[255];
}

// ---------- CSR build: scatter src into dst-sorted order ----------
__global__ void k_csr_scatter(const int* __restrict__ ei, int* __restrict__ cursor,
                              int* __restrict__ col_idx) {
    int e = blockIdx.x * blockDim.x + threadIdx.x;
    if (e >= EE) return;
    int s, d;
    if (e < NE) { s = ei[e]; d = ei[NE + e]; } else { s = d = e - NE; }
    int pos = atomicAdd(&cursor[d], 1);
    col_idx[pos] = s;
}

// ---------- MFMA GEMM: C[MPAD][256] = A[MPAD][K] @ Bt[256][K]^T ----------
__global__ __launch_bounds__(256) void k_gemm(const short* __restrict__ A,
                                              const short* __restrict__ Bt,
                                              int K, float* __restrict__ C) {
    __shared__ char As[BM * BK * 2];   // 16 KB, XOR-swizzled
    __shared__ char Bs[BN * BK * 2];   // 8 KB
    int tid = threadIdx.x;
    int lane = tid & 63;
    int wid = tid >> 6;
    int wm = wid >> 1, wn = wid & 1;               // 2x2 wave grid
    int bm0 = blockIdx.x * BM, bn0 = blockIdx.y * BN;
    int r16 = lane & 15, kg = lane >> 4;

    f32x4 acc[4][2];
    #pragma unroll
    for (int m = 0; m < 4; ++m)
        #pragma unroll
        for (int n = 0; n < 2; ++n) acc[m][n] = (f32x4){0.f, 0.f, 0.f, 0.f};

    for (int k0 = 0; k0 < K; k0 += BK) {
        __syncthreads();
        #pragma unroll
        for (int p = 0; p < 4; ++p) {
            int row = p * 32 + (tid >> 3);
            int cg  = tid & 7;
            uint4 v = *(const uint4*)(A + (size_t)(bm0 + row) * K + k0 + cg * 8);
            *(uint4*)(As + row * 128 + ((cg * 16) ^ ((row & 7) << 4))) = v;
        }
        #pragma unroll
        for (int p = 0; p < 2; ++p) {
            int row = p * 32 + (tid >> 3);
            int cg  = tid & 7;
            uint4 v = *(const uint4*)(Bt + (size_t)(bn0 + row) * K + k0 + cg * 8);
            *(uint4*)(Bs + row * 128 + ((cg * 16) ^ ((row & 7) << 4))) = v;
        }
        __syncthreads();
        #pragma unroll
        for (int kk = 0; kk < 2; ++kk) {
            short8 af[4], bfr[2];
            int kb = (kk * 32 + kg * 8) * 2;
            #pragma unroll
            for (int m = 0; m < 4; ++m) {
                int row = wm * 64 + m * 16 + r16;
                af[m] = *(const short8*)(As + row * 128 + (kb ^ ((row & 7) << 4)));
            }
            #pragma unroll
            for (int n = 0; n < 2; ++n) {
                int row = wn * 32 + n * 16 + r16;
                bfr[n] = *(const short8*)(Bs + row * 128 + (kb ^ ((row & 7) << 4)));
            }
            #pragma unroll
            for (int m = 0; m < 4; ++m)
                #pragma unroll
                for (int n = 0; n < 2; ++n)
                    acc[m][n] = __builtin_amdgcn_mfma_f32_16x16x32_bf16(af[m], bfr[n], acc[m][n], 0, 0, 0);
        }
    }
    #pragma unroll
    for (int m = 0; m < 4; ++m) {
        int row = bm0 + wm * 64 + m * 16 + kg * 4;
        #pragma unroll
        for (int n = 0; n < 2; ++n) {
            int col = bn0 + wn * 32 + n * 16 + r16;
            #pragma unroll
            for (int r = 0; r < 4; ++r)
                C[(size_t)(row + r) * HIDD + col] = acc[m][n][r];
        }
    }
}

// ---------- attention scalars + bf16 cast of xp (wave per node) ----------
__global__ __launch_bounds__(256) void k_att2(const float* __restrict__ xp,
                                              const float* __restrict__ a_src,
                                              const float* __restrict__ a_dst,
                                              float* __restrict__ al_s,
                                              float* __restrict__ al_d,
                                              __hip_bfloat16* __restrict__ xpb) {
    int wid = threadIdx.x >> 6, lane = threadIdx.x & 63;
    int node = blockIdx.x * 4 + wid;
    if (node >= NN) return;
    int hh = lane >> 4, sub = lane & 15;
    float4 v = ((const float4*)(xp + (size_t)node * HIDD))[lane];
    union { __hip_bfloat16 b[4]; ushort4 u; } cv;
    cv.b[0] = __float2bfloat16(v.x); cv.b[1] = __float2bfloat16(v.y);
    cv.b[2] = __float2bfloat16(v.z); cv.b[3] = __float2bfloat16(v.w);
    ((ushort4*)(xpb + (size_t)node * HIDD))[lane] = cv.u;

    float4 ws = ((const float4*)a_src)[lane];
    float4 wd = ((const float4*)a_dst)[lane];
    float s = v.x * ws.x + v.y * ws.y + v.z * ws.z + v.w * ws.w;
    float d = v.x * wd.x + v.y * wd.y + v.z * wd.z + v.w * wd.w;
    #pragma unroll
    for (int m = 1; m < 16; m <<= 1) {
        s += __shfl_xor(s, m, 64);
        d += __shfl_xor(d, m, 64);
    }
    if (sub == 0) {
        al_s[node * NH + hh] = s;
        al_d[node * NH + hh] = d;
    }
}

// ---------- fused edge-softmax + bf16 gather-aggregate + bias/BN/ReLU ----------
__global__ __launch_bounds__(256) void k_gat_agg(
        const int* __restrict__ row_ptr, const int* __restrict__ col_idx,
        const float* __restrict__ al_s, const float* __restrict__ al_d,
        const __hip_bfloat16* __restrict__ xpb,
        const float* __restrict__ bias, const float* __restrict__ bg,
        const float* __restrict__ bb, const float* __restrict__ bm,
        const float* __restrict__ bv,
        float* __restrict__ h, __hip_bfloat16* __restrict__ hb, int wmask) {
    int wid = threadIdx.x >> 6, lane = threadIdx.x & 63;
    int node = blockIdx.x * 4 + wid;
    if (node >= NN) return;
    int lo = row_ptr[node], hi = row_ptr[node + 1];
    int hsel = lane >> 4;
    float4 ad4 = ((const float4*)al_d)[node];
    float adh = sel4(ad4, hsel);

    // pass 1: online softmax max & denominator
    float mrun = -INFINITY, srun = 0.f;
    for (int e = lo; e < hi; ++e) {
        int sc = col_idx[e];
        float4 as4 = ((const float4*)al_s)[sc];
        float lg = sel4(as4, hsel) + adh;
        lg = lg > 0.f ? lg : NEGS * lg;
        float nm = fmaxf(mrun, lg);
        srun = srun * __expf(mrun - nm) + __expf(lg - nm);
        mrun = nm;
    }
    float inv = 1.f / (srun + 1e-16f);

    // pass 2: weighted bf16 gather-accumulate
    float4 acc = {0.f, 0.f, 0.f, 0.f};
    for (int e = lo; e < hi; ++e) {
        int sc = col_idx[e];
        float4 as4 = ((const float4*)al_s)[sc];
        float lg = sel4(as4, hsel) + adh;
        lg = lg > 0.f ? lg : NEGS * lg;
        float alpha = __expf(lg - mrun) * inv;
        ushort4 xv = ((const ushort4*)(xpb + (size_t)sc * HIDD))[lane];
        acc.x = fmaf(alpha, bf2f(xv.x), acc.x);
        acc.y = fmaf(alpha, bf2f(xv.y), acc.y);
        acc.z = fmaf(alpha, bf2f(xv.z), acc.z);
        acc.w = fmaf(alpha, bf2f(xv.w), acc.w);
    }

    // epilogue: bias + BN(eval) + ReLU
    float4 bi = ((const float4*)bias)[lane];
    float4 gg = ((const float4*)bg)[lane];
    float4 be = ((const float4*)bb)[lane];
    float4 mn = ((const float4*)bm)[lane];
    float4 vr = ((const float4*)bv)[lane];
    float4 val;
    val.x = (acc.x + bi.x - mn.x) * rsqrtf(vr.x + BNEPS) * gg.x + be.x;
    val.y = (acc.y + bi.y - mn.y) * rsqrtf(vr.y + BNEPS) * gg.y + be.y;
    val.z = (acc.z + bi.z - mn.z) * rsqrtf(vr.z + BNEPS) * gg.z + be.z;
    val.w = (acc.w + bi.w - mn.w) * rsqrtf(vr.w + BNEPS) * gg.w + be.w;
    val.x = val.x > 0.f ? val.x : 0.f;
    val.y = val.y > 0.f ? val.y : 0.f;
    val.z = val.z > 0.f ? val.z : 0.f;
    val.w = val.w > 0.f ? val.w : 0.f;
    if (wmask & 1)
        ((float4*)h)[(size_t)node * 64 + lane] = val;
    if (wmask & 2) {
        union { __hip_bfloat16 b[4]; ushort4 u; } cv;
        cv.b[0] = __float2bfloat16(val.x); cv.b[1] = __float2bfloat16(val.y);
        cv.b[2] = __float2bfloat16(val.z); cv.b[3] = __float2bfloat16(val.w);
        ((ushort4*)hb)[(size_t)node * 64 + lane] = cv.u;
    }
}

// ---------- parallel pooling: partial sums per (graph, chunk) ----------
__global__ void k_pool2(const float* __restrict__ h, const int* __restrict__ batch,
                        float* __restrict__ partial) {
    int g = blockIdx.x, i = blockIdx.y, col = threadIdx.x;
    int lo = lower_bound_i(batch, NN, g);
    int hi = lower_bound_i(batch, NN, g + 1);
    int len = hi - lo;
    int a = lo + (int)((long)len * i / PSPLIT);
    int b = lo + (int)((long)len * (i + 1) / PSPLIT);
    float acc = 0.f;
    for (int n = a; n < b; ++n) acc += h[(size_t)n * HIDD + col];
    partial[((size_t)g * PSPLIT + i) * HIDD + col] = acc;
}

// ---------- final: sum partials + BN + FC ----------
__global__ __launch_bounds__(64) void k_final(const float* __restrict__ partial,
                                              const float* __restrict__ lg,
                                              const float* __restrict__ lb,
                                              const float* __restrict__ lm,
                                              const float* __restrict__ lv,
                                              const float* __restrict__ fcW,
                                              const float* __restrict__ fcb,
                                              float* __restrict__ out) {
    __shared__ float ps[HIDD];
    int g = blockIdx.x, j = threadIdx.x;
    for (int k = j; k < HIDD; k += 64) {
        float s = 0.f;
        for (int i = 0; i < PSPLIT; ++i)
            s += partial[((size_t)g * PSPLIT + i) * HIDD + k];
        ps[k] = (s - lm[k]) * rsqrtf(lv[k] + BNEPS) * lg[k] + lb[k];
    }
    __syncthreads();
    float acc = 0.f;
    for (int k = 0; k < HIDD; ++k)
        acc = fmaf(ps[k], fcW[k * LATD + j], acc);
    out[g * LATD + j] = acc + fcb[j];
}

extern "C" void kernel_launch(void* const* d_in, const int* in_sizes, int n_in,
                              void* d_out, int out_size, void* d_ws, size_t ws_size,
                              hipStream_t stream) {
    const float* x     = (const float*)d_in[0];
    const int*   ei    = (const int*)d_in[1];
    const int*   batch = (const int*)d_in[2];
    const float* W0    = (const float*)d_in[3];
    const float* Wr    = (const float*)d_in[4];
    const float* asrc  = (const float*)d_in[5];
    const float* adst  = (const float*)d_in[6];
    const float* bconv = (const float*)d_in[7];
    const float* bng   = (const float*)d_in[8];
    const float* bnb   = (const float*)d_in[9];
    const float* bnm   = (const float*)d_in[10];
    const float* bnv   = (const float*)d_in[11];
    const float* lg    = (const float*)d_in[12];
    const float* lb    = (const float*)d_in[13];
    const float* lm    = (const float*)d_in[14];
    const float* lv    = (const float*)d_in[15];
    const float* fcW   = (const float*)d_in[16];
    const float* fcb   = (const float*)d_in[17];
    float* out = (float*)d_out;

    char* w = (char*)d_ws;
    size_t off = 0;
    auto alloc = [&](size_t bytes) {
        char* p = w + off;
        off += (bytes + 255) / 256 * 256;
        return p;
    };
    float* xp    = (float*)alloc((size_t)MPAD * HIDD * 4);  // transformed features fp32
    float* hbuf  = (float*)alloc((size_t)NN * HIDD * 4);    // layer-2 activations fp32
    float* al_s  = (float*)alloc((size_t)NN * NH * 4);
    float* al_d  = (float*)alloc((size_t)NN * NH * 4);
    float* partial = (float*)alloc((size_t)NG * PSPLIT * HIDD * 4);
    __hip_bfloat16* hbx = (__hip_bfloat16*)alloc((size_t)MPAD * IND * 2);   // bf16 x
    __hip_bfloat16* hb2 = (__hip_bfloat16*)alloc((size_t)MPAD * HIDD * 2);  // bf16 activations
    __hip_bfloat16* xpb = (__hip_bfloat16*)alloc((size_t)NN * HIDD * 2);    // bf16 xp
    __hip_bfloat16* Wt  = (__hip_bfloat16*)alloc((size_t)HIDD * HIDD * 2);  // bf16 W^T
    int* deg     = (int*)alloc((size_t)NN * 4);
    int* row_ptr = (int*)alloc((size_t)(NN + 1) * 4);
    int* cursor  = (int*)alloc((size_t)NN * 4);
    int* col_idx = (int*)alloc((size_t)EE * 4);

    // ---- CSR build (dst-sorted edges) ----
    hipMemsetAsync(deg, 0, (size_t)NN * sizeof(int), stream);
    hipLaunchKernelGGL(k_hist, dim3((EE + 255) / 256), dim3(256), 0, stream, ei, deg);
    hipLaunchKernelGGL(k_scan256, dim3(1), dim3(256), 0, stream, deg, row_ptr, cursor);
    hipLaunchKernelGGL(k_csr_scatter, dim3((EE + 255) / 256), dim3(256), 0, stream,
                       ei, cursor, col_idx);

    hipLaunchKernelGGL(k_cast_x, dim3((NN * IND / 4 + 255) / 256), dim3(256), 0, stream, x, hbx);

    for (int layer = 0; layer < 3; ++layer) {
        const float* W = (layer == 0) ? W0 : (Wr + (size_t)(layer - 1) * HIDD * HIDD);
        int K          = (layer == 0) ? IND : HIDD;
        const __hip_bfloat16* Ab = (layer == 0) ? hbx : hb2;
        int wmask      = (layer == 2) ? 1 : 2;   // fp32 h only for last layer; bf16 only before

        hipLaunchKernelGGL(k_cast_wt, dim3(K), dim3(HIDD), 0, stream, W, K, Wt);
        hipLaunchKernelGGL(k_gemm, dim3(MPAD / BM, HIDD / BN), dim3(256), 0, stream,
                           (const short*)Ab, (const short*)Wt, K, xp);
        hipLaunchKernelGGL(k_att2, dim3((NN + 3) / 4), dim3(256), 0, stream,
                           xp, asrc + layer * NH * NC, adst + layer * NH * NC, al_s, al_d, xpb);
        hipLaunchKernelGGL(k_gat_agg, dim3((NN + 3) / 4), dim3(256), 0, stream,
                           row_ptr, col_idx, al_s, al_d, xpb,
                           bconv + layer * HIDD, bng + layer * HIDD, bnb + layer * HIDD,
                           bnm + layer * HIDD, bnv + layer * HIDD, hbuf, hb2, wmask);
    }

    hipLaunchKernelGGL(k_pool2, dim3(NG, PSPLIT), dim3(HIDD), 0, stream, hbuf, batch, partial);
    hipLaunchKernelGGL(k_final, dim3(NG), dim3(LATD), 0, stream,
                       partial, lg, lb, lm, lv, fcW, fcb, out);
}

// Round 5
// 253.785 us; speedup vs baseline: 8.3582x; 1.6096x over previous
//
#include <hip/hip_runtime.h>
#include <hip/hip_bf16.h>
#include <cmath>

#define NN   20000              // nodes
#define NE   320000             // raw edges
#define EE   (NE + NN)          // edges incl. self-loops
#define NG   64                 // graphs
#define NH   4                  // heads
#define NC   64                 // channels/head
#define HIDD 256                // NH*NC
#define IND  128                // input feature dim
#define LATD 64                 // latent dim
#define NEGS 0.2f
#define BNEPS 1e-5f
#define MPAD 20096              // 157 * 128 (GEMM M padding)
#define PSPLIT 16               // pooling chunks per graph

// GEMM tile
#define BM 128
#define BN 64
#define BK 64

typedef __attribute__((ext_vector_type(8))) short short8;
typedef __attribute__((ext_vector_type(4))) float f32x4;

__device__ inline int lower_bound_i(const int* __restrict__ b, int n, int key) {
    int lo = 0, hi = n;
    while (lo < hi) { int mid = (lo + hi) >> 1; if (b[mid] < key) lo = mid + 1; else hi = mid; }
    return lo;
}

__device__ inline float sel4(float4 v, int h) {
    float r = v.x;
    r = (h == 1) ? v.y : r;
    r = (h == 2) ? v.z : r;
    r = (h == 3) ? v.w : r;
    return r;
}

__device__ inline float bf2f(unsigned short u) {
    return __uint_as_float(((unsigned int)u) << 16);
}

// ---------- fp32 -> bf16 cast of x ----------
__global__ void k_cast_x(const float* __restrict__ x, __hip_bfloat16* __restrict__ hbx) {
    int i = blockIdx.x * blockDim.x + threadIdx.x;     // over NN*IND/4
    if (i >= NN * IND / 4) return;
    float4 v = ((const float4*)x)[i];
    union { __hip_bfloat16 b[4]; ushort4 u; } cv;
    cv.b[0] = __float2bfloat16(v.x); cv.b[1] = __float2bfloat16(v.y);
    cv.b[2] = __float2bfloat16(v.z); cv.b[3] = __float2bfloat16(v.w);
    ((ushort4*)hbx)[i] = cv.u;
}

// ---------- W[K][256] -> Wt[256][K] bf16 ----------
__global__ void k_cast_wt(const float* __restrict__ W, int K, __hip_bfloat16* __restrict__ Wt) {
    int k = blockIdx.x;          // K blocks
    int n = threadIdx.x;         // 256
    Wt[(size_t)n * K + k] = __float2bfloat16(W[(size_t)k * HIDD + n]);
}

// ---------- CSR build: histogram of dst ----------
__global__ void k_hist(const int* __restrict__ ei, int* __restrict__ deg) {
    int e = blockIdx.x * blockDim.x + threadIdx.x;
    if (e >= EE) return;
    int d = (e < NE) ? ei[NE + e] : (e - NE);
    atomicAdd(&deg[d], 1);
}

// ---------- CSR build: chunked exclusive scan (1 block, 256 threads) ----------
#define SCHUNK ((NN + 255) / 256)
__global__ __launch_bounds__(256) void k_scan256(const int* __restrict__ deg,
                                                 int* __restrict__ row_ptr,
                                                 int* __restrict__ cursor) {
    __shared__ int part[256];
    int tid = threadIdx.x;
    int base = tid * SCHUNK;
    int cnt = NN - base; cnt = cnt < 0 ? 0 : (cnt > SCHUNK ? SCHUNK : cnt);
    int sum = 0;
    for (int j = 0; j < cnt; ++j) sum += deg[base + j];
    part[tid] = sum;
    __syncthreads();
    for (int off = 1; off < 256; off <<= 1) {
        int t = (tid >= off) ? part[tid - off] : 0;
        __syncthreads();
        part[tid] += t;
        __syncthreads();
    }
    int excl = part[tid] - sum;
    for (int j = 0; j < cnt; ++j) {
        row_ptr[base + j] = excl; cursor[base + j] = excl;
        excl += deg[base + j];
    }
    if (tid == 255) row_ptr[NN] = part[255];
}

// ---------- CSR build: scatter src into dst-sorted order ----------
__global__ void k_csr_scatter(const int* __restrict__ ei, int* __restrict__ cursor,
                              int* __restrict__ col_idx) {
    int e = blockIdx.x * blockDim.x + threadIdx.x;
    if (e >= EE) return;
    int s, d;
    if (e < NE) { s = ei[e]; d = ei[NE + e]; } else { s = d = e - NE; }
    int pos = atomicAdd(&cursor[d], 1);
    col_idx[pos] = s;
}

// ---------- MFMA GEMM: C[MPAD][256] = A[MPAD][K] @ Bt[256][K]^T ----------
__global__ __launch_bounds__(256) void k_gemm(const short* __restrict__ A,
                                              const short* __restrict__ Bt,
                                              int K, float* __restrict__ C) {
    __shared__ char As[BM * BK * 2];   // 16 KB, XOR-swizzled
    __shared__ char Bs[BN * BK * 2];   // 8 KB
    int tid = threadIdx.x;
    int lane = tid & 63;
    int wid = tid >> 6;
    int wm = wid >> 1, wn = wid & 1;               // 2x2 wave grid
    int bm0 = blockIdx.x * BM, bn0 = blockIdx.y * BN;
    int r16 = lane & 15, kg = lane >> 4;

    f32x4 acc[4][2];
    #pragma unroll
    for (int m = 0; m < 4; ++m)
        #pragma unroll
        for (int n = 0; n < 2; ++n) acc[m][n] = (f32x4){0.f, 0.f, 0.f, 0.f};

    for (int k0 = 0; k0 < K; k0 += BK) {
        __syncthreads();
        #pragma unroll
        for (int p = 0; p < 4; ++p) {
            int row = p * 32 + (tid >> 3);
            int cg  = tid & 7;
            uint4 v = *(const uint4*)(A + (size_t)(bm0 + row) * K + k0 + cg * 8);
            *(uint4*)(As + row * 128 + ((cg * 16) ^ ((row & 7) << 4))) = v;
        }
        #pragma unroll
        for (int p = 0; p < 2; ++p) {
            int row = p * 32 + (tid >> 3);
            int cg  = tid & 7;
            uint4 v = *(const uint4*)(Bt + (size_t)(bn0 + row) * K + k0 + cg * 8);
            *(uint4*)(Bs + row * 128 + ((cg * 16) ^ ((row & 7) << 4))) = v;
        }
        __syncthreads();
        #pragma unroll
        for (int kk = 0; kk < 2; ++kk) {
            short8 af[4], bfr[2];
            int kb = (kk * 32 + kg * 8) * 2;
            #pragma unroll
            for (int m = 0; m < 4; ++m) {
                int row = wm * 64 + m * 16 + r16;
                af[m] = *(const short8*)(As + row * 128 + (kb ^ ((row & 7) << 4)));
            }
            #pragma unroll
            for (int n = 0; n < 2; ++n) {
                int row = wn * 32 + n * 16 + r16;
                bfr[n] = *(const short8*)(Bs + row * 128 + (kb ^ ((row & 7) << 4)));
            }
            #pragma unroll
            for (int m = 0; m < 4; ++m)
                #pragma unroll
                for (int n = 0; n < 2; ++n)
                    acc[m][n] = __builtin_amdgcn_mfma_f32_16x16x32_bf16(af[m], bfr[n], acc[m][n], 0, 0, 0);
        }
    }
    #pragma unroll
    for (int m = 0; m < 4; ++m) {
        int row = bm0 + wm * 64 + m * 16 + kg * 4;
        #pragma unroll
        for (int n = 0; n < 2; ++n) {
            int col = bn0 + wn * 32 + n * 16 + r16;
            #pragma unroll
            for (int r = 0; r < 4; ++r)
                C[(size_t)(row + r) * HIDD + col] = acc[m][n][r];
        }
    }
}

// ---------- attention scalars + bf16 cast of xp (wave per node) ----------
__global__ __launch_bounds__(256) void k_att2(const float* __restrict__ xp,
                                              const float* __restrict__ a_src,
                                              const float* __restrict__ a_dst,
                                              float* __restrict__ al_s,
                                              float* __restrict__ al_d,
                                              __hip_bfloat16* __restrict__ xpb) {
    int wid = threadIdx.x >> 6, lane = threadIdx.x & 63;
    int node = blockIdx.x * 4 + wid;
    if (node >= NN) return;
    int hh = lane >> 4, sub = lane & 15;
    float4 v = ((const float4*)(xp + (size_t)node * HIDD))[lane];
    union { __hip_bfloat16 b[4]; ushort4 u; } cv;
    cv.b[0] = __float2bfloat16(v.x); cv.b[1] = __float2bfloat16(v.y);
    cv.b[2] = __float2bfloat16(v.z); cv.b[3] = __float2bfloat16(v.w);
    ((ushort4*)(xpb + (size_t)node * HIDD))[lane] = cv.u;

    float4 ws = ((const float4*)a_src)[lane];
    float4 wd = ((const float4*)a_dst)[lane];
    float s = v.x * ws.x + v.y * ws.y + v.z * ws.z + v.w * ws.w;
    float d = v.x * wd.x + v.y * wd.y + v.z * wd.z + v.w * wd.w;
    #pragma unroll
    for (int m = 1; m < 16; m <<= 1) {
        s += __shfl_xor(s, m, 64);
        d += __shfl_xor(d, m, 64);
    }
    if (sub == 0) {
        al_s[node * NH + hh] = s;
        al_d[node * NH + hh] = d;
    }
}

// ---------- fused single-pass edge-softmax + bf16 gather-aggregate + bias/BN/ReLU ----------
// alpha_e = exp(lg_e) / sum(exp(lg)) -- identical to max-shifted form; logits are O(5).
__global__ __launch_bounds__(256) void k_gat_agg(
        const int* __restrict__ row_ptr, const int* __restrict__ col_idx,
        const float* __restrict__ al_s, const float* __restrict__ al_d,
        const __hip_bfloat16* __restrict__ xpb,
        const float* __restrict__ bias, const float* __restrict__ bg,
        const float* __restrict__ bb, const float* __restrict__ bm,
        const float* __restrict__ bv,
        float* __restrict__ h, __hip_bfloat16* __restrict__ hb, int wmask) {
    int wid = threadIdx.x >> 6, lane = threadIdx.x & 63;
    int node = blockIdx.x * 4 + wid;
    if (node >= NN) return;
    int lo = row_ptr[node], hi = row_ptr[node + 1];
    int hsel = lane >> 4;
    float adh = sel4(((const float4*)al_d)[node], hsel);

    float4 acc0 = {0,0,0,0}, acc1 = {0,0,0,0}, acc2 = {0,0,0,0}, acc3 = {0,0,0,0};
    float den0 = 0.f, den1 = 0.f, den2 = 0.f, den3 = 0.f;

    int e = lo;
    for (; e + 3 < hi; e += 4) {
        int sc0 = col_idx[e], sc1 = col_idx[e + 1], sc2 = col_idx[e + 2], sc3 = col_idx[e + 3];
        float as0 = al_s[sc0 * NH + hsel];
        float as1 = al_s[sc1 * NH + hsel];
        float as2 = al_s[sc2 * NH + hsel];
        float as3 = al_s[sc3 * NH + hsel];
        ushort4 xv0 = ((const ushort4*)(xpb + (size_t)sc0 * HIDD))[lane];
        ushort4 xv1 = ((const ushort4*)(xpb + (size_t)sc1 * HIDD))[lane];
        ushort4 xv2 = ((const ushort4*)(xpb + (size_t)sc2 * HIDD))[lane];
        ushort4 xv3 = ((const ushort4*)(xpb + (size_t)sc3 * HIDD))[lane];
        float l0 = as0 + adh; l0 = l0 > 0.f ? l0 : NEGS * l0;
        float l1 = as1 + adh; l1 = l1 > 0.f ? l1 : NEGS * l1;
        float l2 = as2 + adh; l2 = l2 > 0.f ? l2 : NEGS * l2;
        float l3 = as3 + adh; l3 = l3 > 0.f ? l3 : NEGS * l3;
        float w0 = __expf(l0), w1 = __expf(l1), w2 = __expf(l2), w3 = __expf(l3);
        den0 += w0; den1 += w1; den2 += w2; den3 += w3;
        acc0.x = fmaf(w0, bf2f(xv0.x), acc0.x); acc0.y = fmaf(w0, bf2f(xv0.y), acc0.y);
        acc0.z = fmaf(w0, bf2f(xv0.z), acc0.z); acc0.w = fmaf(w0, bf2f(xv0.w), acc0.w);
        acc1.x = fmaf(w1, bf2f(xv1.x), acc1.x); acc1.y = fmaf(w1, bf2f(xv1.y), acc1.y);
        acc1.z = fmaf(w1, bf2f(xv1.z), acc1.z); acc1.w = fmaf(w1, bf2f(xv1.w), acc1.w);
        acc2.x = fmaf(w2, bf2f(xv2.x), acc2.x); acc2.y = fmaf(w2, bf2f(xv2.y), acc2.y);
        acc2.z = fmaf(w2, bf2f(xv2.z), acc2.z); acc2.w = fmaf(w2, bf2f(xv2.w), acc2.w);
        acc3.x = fmaf(w3, bf2f(xv3.x), acc3.x); acc3.y = fmaf(w3, bf2f(xv3.y), acc3.y);
        acc3.z = fmaf(w3, bf2f(xv3.z), acc3.z); acc3.w = fmaf(w3, bf2f(xv3.w), acc3.w);
    }
    for (; e < hi; ++e) {
        int sc = col_idx[e];
        float as = al_s[sc * NH + hsel];
        ushort4 xv = ((const ushort4*)(xpb + (size_t)sc * HIDD))[lane];
        float l = as + adh; l = l > 0.f ? l : NEGS * l;
        float wt = __expf(l);
        den0 += wt;
        acc0.x = fmaf(wt, bf2f(xv.x), acc0.x); acc0.y = fmaf(wt, bf2f(xv.y), acc0.y);
        acc0.z = fmaf(wt, bf2f(xv.z), acc0.z); acc0.w = fmaf(wt, bf2f(xv.w), acc0.w);
    }

    float inv = 1.f / ((den0 + den1) + (den2 + den3) + 1e-16f);
    float4 acc;
    acc.x = ((acc0.x + acc1.x) + (acc2.x + acc3.x)) * inv;
    acc.y = ((acc0.y + acc1.y) + (acc2.y + acc3.y)) * inv;
    acc.z = ((acc0.z + acc1.z) + (acc2.z + acc3.z)) * inv;
    acc.w = ((acc0.w + acc1.w) + (acc2.w + acc3.w)) * inv;

    // epilogue: bias + BN(eval) + ReLU
    float4 bi = ((const float4*)bias)[lane];
    float4 gg = ((const float4*)bg)[lane];
    float4 be = ((const float4*)bb)[lane];
    float4 mn = ((const float4*)bm)[lane];
    float4 vr = ((const float4*)bv)[lane];
    float4 val;
    val.x = (acc.x + bi.x - mn.x) * rsqrtf(vr.x + BNEPS) * gg.x + be.x;
    val.y = (acc.y + bi.y - mn.y) * rsqrtf(vr.y + BNEPS) * gg.y + be.y;
    val.z = (acc.z + bi.z - mn.z) * rsqrtf(vr.z + BNEPS) * gg.z + be.z;
    val.w = (acc.w + bi.w - mn.w) * rsqrtf(vr.w + BNEPS) * gg.w + be.w;
    val.x = val.x > 0.f ? val.x : 0.f;
    val.y = val.y > 0.f ? val.y : 0.f;
    val.z = val.z > 0.f ? val.z : 0.f;
    val.w = val.w > 0.f ? val.w : 0.f;
    if (wmask & 1)
        ((float4*)h)[(size_t)node * 64 + lane] = val;
    if (wmask & 2) {
        union { __hip_bfloat16 b[4]; ushort4 u; } cv;
        cv.b[0] = __float2bfloat16(val.x); cv.b[1] = __float2bfloat16(val.y);
        cv.b[2] = __float2bfloat16(val.z); cv.b[3] = __float2bfloat16(val.w);
        ((ushort4*)hb)[(size_t)node * 64 + lane] = cv.u;
    }
}

// ---------- parallel pooling: partial sums per (graph, chunk) ----------
__global__ void k_pool2(const float* __restrict__ h, const int* __restrict__ batch,
                        float* __restrict__ partial) {
    int g = blockIdx.x, i = blockIdx.y, col = threadIdx.x;
    int lo = lower_bound_i(batch, NN, g);
    int hi = lower_bound_i(batch, NN, g + 1);
    int len = hi - lo;
    int a = lo + (int)((long)len * i / PSPLIT);
    int b = lo + (int)((long)len * (i + 1) / PSPLIT);
    float acc = 0.f;
    for (int n = a; n < b; ++n) acc += h[(size_t)n * HIDD + col];
    partial[((size_t)g * PSPLIT + i) * HIDD + col] = acc;
}

// ---------- final: sum partials + BN + FC ----------
__global__ __launch_bounds__(64) void k_final(const float* __restrict__ partial,
                                              const float* __restrict__ lg,
                                              const float* __restrict__ lb,
                                              const float* __restrict__ lm,
                                              const float* __restrict__ lv,
                                              const float* __restrict__ fcW,
                                              const float* __restrict__ fcb,
                                              float* __restrict__ out) {
    __shared__ float ps[HIDD];
    int g = blockIdx.x, j = threadIdx.x;
    for (int k = j; k < HIDD; k += 64) {
        float s = 0.f;
        for (int i = 0; i < PSPLIT; ++i)
            s += partial[((size_t)g * PSPLIT + i) * HIDD + k];
        ps[k] = (s - lm[k]) * rsqrtf(lv[k] + BNEPS) * lg[k] + lb[k];
    }
    __syncthreads();
    float acc = 0.f;
    for (int k = 0; k < HIDD; ++k)
        acc = fmaf(ps[k], fcW[k * LATD + j], acc);
    out[g * LATD + j] = acc + fcb[j];
}

extern "C" void kernel_launch(void* const* d_in, const int* in_sizes, int n_in,
                              void* d_out, int out_size, void* d_ws, size_t ws_size,
                              hipStream_t stream) {
    const float* x     = (const float*)d_in[0];
    const int*   ei    = (const int*)d_in[1];
    const int*   batch = (const int*)d_in[2];
    const float* W0    = (const float*)d_in[3];
    const float* Wr    = (const float*)d_in[4];
    const float* asrc  = (const float*)d_in[5];
    const float* adst  = (const float*)d_in[6];
    const float* bconv = (const float*)d_in[7];
    const float* bng   = (const float*)d_in[8];
    const float* bnb   = (const float*)d_in[9];
    const float* bnm   = (const float*)d_in[10];
    const float* bnv   = (const float*)d_in[11];
    const float* lg    = (const float*)d_in[12];
    const float* lb    = (const float*)d_in[13];
    const float* lm    = (const float*)d_in[14];
    const float* lv    = (const float*)d_in[15];
    const float* fcW   = (const float*)d_in[16];
    const float* fcb   = (const float*)d_in[17];
    float* out = (float*)d_out;

    char* w = (char*)d_ws;
    size_t off = 0;
    auto alloc = [&](size_t bytes) {
        char* p = w + off;
        off += (bytes + 255) / 256 * 256;
        return p;
    };
    float* xp    = (float*)alloc((size_t)MPAD * HIDD * 4);  // transformed features fp32
    float* hbuf  = (float*)alloc((size_t)NN * HIDD * 4);    // layer-2 activations fp32
    float* al_s  = (float*)alloc((size_t)NN * NH * 4);
    float* al_d  = (float*)alloc((size_t)NN * NH * 4);
    float* partial = (float*)alloc((size_t)NG * PSPLIT * HIDD * 4);
    __hip_bfloat16* hbx = (__hip_bfloat16*)alloc((size_t)MPAD * IND * 2);   // bf16 x
    __hip_bfloat16* hb2 = (__hip_bfloat16*)alloc((size_t)MPAD * HIDD * 2);  // bf16 activations
    __hip_bfloat16* xpb = (__hip_bfloat16*)alloc((size_t)NN * HIDD * 2);    // bf16 xp
    __hip_bfloat16* Wt  = (__hip_bfloat16*)alloc((size_t)HIDD * HIDD * 2);  // bf16 W^T
    int* deg     = (int*)alloc((size_t)NN * 4);
    int* row_ptr = (int*)alloc((size_t)(NN + 1) * 4);
    int* cursor  = (int*)alloc((size_t)NN * 4);
    int* col_idx = (int*)alloc((size_t)EE * 4);

    // ---- CSR build (dst-sorted edges) ----
    hipMemsetAsync(deg, 0, (size_t)NN * sizeof(int), stream);
    hipLaunchKernelGGL(k_hist, dim3((EE + 255) / 256), dim3(256), 0, stream, ei, deg);
    hipLaunchKernelGGL(k_scan256, dim3(1), dim3(256), 0, stream, deg, row_ptr, cursor);
    hipLaunchKernelGGL(k_csr_scatter, dim3((EE + 255) / 256), dim3(256), 0, stream,
                       ei, cursor, col_idx);

    hipLaunchKernelGGL(k_cast_x, dim3((NN * IND / 4 + 255) / 256), dim3(256), 0, stream, x, hbx);

    for (int layer = 0; layer < 3; ++layer) {
        const float* W = (layer == 0) ? W0 : (Wr + (size_t)(layer - 1) * HIDD * HIDD);
        int K          = (layer == 0) ? IND : HIDD;
        const __hip_bfloat16* Ab = (layer == 0) ? hbx : hb2;
        int wmask      = (layer == 2) ? 1 : 2;   // fp32 h only for last layer; bf16 only before

        hipLaunchKernelGGL(k_cast_wt, dim3(K), dim3(HIDD), 0, stream, W, K, Wt);
        hipLaunchKernelGGL(k_gemm, dim3(MPAD / BM, HIDD / BN), dim3(256), 0, stream,
                           (const short*)Ab, (const short*)Wt, K, xp);
        hipLaunchKernelGGL(k_att2, dim3((NN + 3) / 4), dim3(256), 0, stream,
                           xp, asrc + layer * NH * NC, adst + layer * NH * NC, al_s, al_d, xpb);
        hipLaunchKernelGGL(k_gat_agg, dim3((NN + 3) / 4), dim3(256), 0, stream,
                           row_ptr, col_idx, al_s, al_d, xpb,
                           bconv + layer * HIDD, bng + layer * HIDD, bnb + layer * HIDD,
                           bnm + layer * HIDD, bnv + layer * HIDD, hbuf, hb2, wmask);
    }

    hipLaunchKernelGGL(k_pool2, dim3(NG, PSPLIT), dim3(HIDD), 0, stream, hbuf, batch, partial);
    hipLaunchKernelGGL(k_final, dim3(NG), dim3(LATD), 0, stream,
                       partial, lg, lb, lm, lv, fcW, fcb, out);
}

// Round 6
// 205.552 us; speedup vs baseline: 10.3195x; 1.2347x over previous
//
#include <hip/hip_runtime.h>
#include <hip/hip_bf16.h>
#include <cmath>

#define NN   20000              // nodes
#define NE   320000             // raw edges
#define EE   (NE + NN)          // edges incl. self-loops
#define NG   64                 // graphs
#define NH   4                  // heads
#define NC   64                 // channels/head
#define HIDD 256                // NH*NC
#define IND  128                // input feature dim
#define LATD 64                 // latent dim
#define NEGS 0.2f
#define BNEPS 1e-5f
#define MPAD 20096              // 157 * 128 (GEMM M padding)
#define PSPLIT 16               // pooling chunks per graph
#define NB   ((NN + 255) / 256) // scan blocks (79)

// GEMM tile
#define BM 128
#define BN 64
#define BK 64

typedef __attribute__((ext_vector_type(8))) short short8;
typedef __attribute__((ext_vector_type(4))) float f32x4;

__device__ inline int lower_bound_i(const int* __restrict__ b, int n, int key) {
    int lo = 0, hi = n;
    while (lo < hi) { int mid = (lo + hi) >> 1; if (b[mid] < key) lo = mid + 1; else hi = mid; }
    return lo;
}

__device__ inline float sel4(float4 v, int h) {
    float r = v.x;
    r = (h == 1) ? v.y : r;
    r = (h == 2) ? v.z : r;
    r = (h == 3) ? v.w : r;
    return r;
}

__device__ inline float bf2f(unsigned short u) {
    return __uint_as_float(((unsigned int)u) << 16);
}

// ---------- fp32 -> bf16 cast of x ----------
__global__ void k_cast_x(const float* __restrict__ x, __hip_bfloat16* __restrict__ hbx) {
    int i = blockIdx.x * blockDim.x + threadIdx.x;     // over NN*IND/4
    if (i >= NN * IND / 4) return;
    float4 v = ((const float4*)x)[i];
    union { __hip_bfloat16 b[4]; ushort4 u; } cv;
    cv.b[0] = __float2bfloat16(v.x); cv.b[1] = __float2bfloat16(v.y);
    cv.b[2] = __float2bfloat16(v.z); cv.b[3] = __float2bfloat16(v.w);
    ((ushort4*)hbx)[i] = cv.u;
}

// ---------- W[K][256] -> Wt[256][K] bf16 ----------
__global__ void k_cast_wt(const float* __restrict__ W, int K, __hip_bfloat16* __restrict__ Wt) {
    int k = blockIdx.x;          // K blocks
    int n = threadIdx.x;         // 256
    Wt[(size_t)n * K + k] = __float2bfloat16(W[(size_t)k * HIDD + n]);
}

// ---------- CSR build: histogram of dst ----------
__global__ void k_hist(const int* __restrict__ ei, int* __restrict__ deg) {
    int e = blockIdx.x * blockDim.x + threadIdx.x;
    if (e >= EE) return;
    int d = (e < NE) ? ei[NE + e] : (e - NE);
    atomicAdd(&deg[d], 1);
}

// ---------- CSR build: 3-phase parallel exclusive scan ----------
__global__ __launch_bounds__(256) void k_blocksum(const int* __restrict__ deg,
                                                  int* __restrict__ bsum) {
    __shared__ int s[256];
    int i = blockIdx.x * 256 + threadIdx.x;
    s[threadIdx.x] = (i < NN) ? deg[i] : 0;
    __syncthreads();
    for (int off = 128; off > 0; off >>= 1) {
        if (threadIdx.x < off) s[threadIdx.x] += s[threadIdx.x + off];
        __syncthreads();
    }
    if (threadIdx.x == 0) bsum[blockIdx.x] = s[0];
}

__global__ __launch_bounds__(128) void k_scanbs(const int* __restrict__ bsum,
                                                int* __restrict__ boff,
                                                int* __restrict__ row_ptr) {
    __shared__ int s[128];
    int tid = threadIdx.x;
    int v = (tid < NB) ? bsum[tid] : 0;
    s[tid] = v;
    __syncthreads();
    for (int off = 1; off < 128; off <<= 1) {
        int t = (tid >= off) ? s[tid - off] : 0;
        __syncthreads();
        s[tid] += t;
        __syncthreads();
    }
    if (tid < NB) boff[tid] = s[tid] - v;          // exclusive block offset
    if (tid == NB - 1) row_ptr[NN] = s[tid];       // total (= EE)
}

__global__ __launch_bounds__(256) void k_scanapply(const int* __restrict__ deg,
                                                   const int* __restrict__ boff,
                                                   int* __restrict__ row_ptr,
                                                   int* __restrict__ cursor) {
    __shared__ int s[256];
    int i = blockIdx.x * 256 + threadIdx.x;
    int v = (i < NN) ? deg[i] : 0;
    s[threadIdx.x] = v;
    __syncthreads();
    for (int off = 1; off < 256; off <<= 1) {
        int t = (threadIdx.x >= off) ? s[threadIdx.x - off] : 0;
        __syncthreads();
        s[threadIdx.x] += t;
        __syncthreads();
    }
    if (i < NN) {
        int excl = boff[blockIdx.x] + s[threadIdx.x] - v;
        row_ptr[i] = excl; cursor[i] = excl;
    }
}

// ---------- CSR build: scatter src into dst-sorted order ----------
__global__ void k_csr_scatter(const int* __restrict__ ei, int* __restrict__ cursor,
                              int* __restrict__ col_idx) {
    int e = blockIdx.x * blockDim.x + threadIdx.x;
    if (e >= EE) return;
    int s, d;
    if (e < NE) { s = ei[e]; d = ei[NE + e]; } else { s = d = e - NE; }
    int pos = atomicAdd(&cursor[d], 1);
    col_idx[pos] = s;
}

// ---------- MFMA GEMM: Cb[MPAD][256] = A[MPAD][K] @ Bt[256][K]^T (bf16 out) ----------
__global__ __launch_bounds__(256) void k_gemm(const short* __restrict__ A,
                                              const short* __restrict__ Bt,
                                              int K, __hip_bfloat16* __restrict__ Cb) {
    __shared__ char As[BM * BK * 2];   // 16 KB, XOR-swizzled
    __shared__ char Bs[BN * BK * 2];   // 8 KB
    int tid = threadIdx.x;
    int lane = tid & 63;
    int wid = tid >> 6;
    int wm = wid >> 1, wn = wid & 1;               // 2x2 wave grid
    int bm0 = blockIdx.x * BM, bn0 = blockIdx.y * BN;
    int r16 = lane & 15, kg = lane >> 4;

    f32x4 acc[4][2];
    #pragma unroll
    for (int m = 0; m < 4; ++m)
        #pragma unroll
        for (int n = 0; n < 2; ++n) acc[m][n] = (f32x4){0.f, 0.f, 0.f, 0.f};

    for (int k0 = 0; k0 < K; k0 += BK) {
        __syncthreads();
        #pragma unroll
        for (int p = 0; p < 4; ++p) {
            int row = p * 32 + (tid >> 3);
            int cg  = tid & 7;
            uint4 v = *(const uint4*)(A + (size_t)(bm0 + row) * K + k0 + cg * 8);
            *(uint4*)(As + row * 128 + ((cg * 16) ^ ((row & 7) << 4))) = v;
        }
        #pragma unroll
        for (int p = 0; p < 2; ++p) {
            int row = p * 32 + (tid >> 3);
            int cg  = tid & 7;
            uint4 v = *(const uint4*)(Bt + (size_t)(bn0 + row) * K + k0 + cg * 8);
            *(uint4*)(Bs + row * 128 + ((cg * 16) ^ ((row & 7) << 4))) = v;
        }
        __syncthreads();
        #pragma unroll
        for (int kk = 0; kk < 2; ++kk) {
            short8 af[4], bfr[2];
            int kb = (kk * 32 + kg * 8) * 2;
            #pragma unroll
            for (int m = 0; m < 4; ++m) {
                int row = wm * 64 + m * 16 + r16;
                af[m] = *(const short8*)(As + row * 128 + (kb ^ ((row & 7) << 4)));
            }
            #pragma unroll
            for (int n = 0; n < 2; ++n) {
                int row = wn * 32 + n * 16 + r16;
                bfr[n] = *(const short8*)(Bs + row * 128 + (kb ^ ((row & 7) << 4)));
            }
            #pragma unroll
            for (int m = 0; m < 4; ++m)
                #pragma unroll
                for (int n = 0; n < 2; ++n)
                    acc[m][n] = __builtin_amdgcn_mfma_f32_16x16x32_bf16(af[m], bfr[n], acc[m][n], 0, 0, 0);
        }
    }
    #pragma unroll
    for (int m = 0; m < 4; ++m) {
        int row = bm0 + wm * 64 + m * 16 + kg * 4;
        #pragma unroll
        for (int n = 0; n < 2; ++n) {
            int col = bn0 + wn * 32 + n * 16 + r16;
            #pragma unroll
            for (int r = 0; r < 4; ++r)
                Cb[(size_t)(row + r) * HIDD + col] = __float2bfloat16(acc[m][n][r]);
        }
    }
}

// ---------- attention scalars from bf16 xp (wave per node) ----------
__global__ __launch_bounds__(256) void k_att2(const __hip_bfloat16* __restrict__ xpb,
                                              const float* __restrict__ a_src,
                                              const float* __restrict__ a_dst,
                                              float* __restrict__ al_s,
                                              float* __restrict__ al_d) {
    int wid = threadIdx.x >> 6, lane = threadIdx.x & 63;
    int node = blockIdx.x * 4 + wid;
    if (node >= NN) return;
    int hh = lane >> 4, sub = lane & 15;
    ushort4 u = ((const ushort4*)(xpb + (size_t)node * HIDD))[lane];
    float4 v = {bf2f(u.x), bf2f(u.y), bf2f(u.z), bf2f(u.w)};
    float4 ws = ((const float4*)a_src)[lane];
    float4 wd = ((const float4*)a_dst)[lane];
    float s = v.x * ws.x + v.y * ws.y + v.z * ws.z + v.w * ws.w;
    float d = v.x * wd.x + v.y * wd.y + v.z * wd.z + v.w * wd.w;
    #pragma unroll
    for (int m = 1; m < 16; m <<= 1) {
        s += __shfl_xor(s, m, 64);
        d += __shfl_xor(d, m, 64);
    }
    if (sub == 0) {
        al_s[node * NH + hh] = s;
        al_d[node * NH + hh] = d;
    }
}

// ---------- fused single-pass edge-softmax + bf16 gather-aggregate + bias/BN/ReLU ----------
__global__ __launch_bounds__(256) void k_gat_agg(
        const int* __restrict__ row_ptr, const int* __restrict__ col_idx,
        const float* __restrict__ al_s, const float* __restrict__ al_d,
        const __hip_bfloat16* __restrict__ xpb,
        const float* __restrict__ bias, const float* __restrict__ bg,
        const float* __restrict__ bb, const float* __restrict__ bm,
        const float* __restrict__ bv,
        float* __restrict__ h, __hip_bfloat16* __restrict__ hb, int wmask) {
    int wid = threadIdx.x >> 6, lane = threadIdx.x & 63;
    int node = blockIdx.x * 4 + wid;
    if (node >= NN) return;
    int lo = row_ptr[node], hi = row_ptr[node + 1];
    int hsel = lane >> 4;
    float adh = sel4(((const float4*)al_d)[node], hsel);

    float4 acc0 = {0,0,0,0}, acc1 = {0,0,0,0}, acc2 = {0,0,0,0}, acc3 = {0,0,0,0};
    float den0 = 0.f, den1 = 0.f, den2 = 0.f, den3 = 0.f;

    int e = lo;
    for (; e + 3 < hi; e += 4) {
        int sc0 = col_idx[e], sc1 = col_idx[e + 1], sc2 = col_idx[e + 2], sc3 = col_idx[e + 3];
        float as0 = al_s[sc0 * NH + hsel];
        float as1 = al_s[sc1 * NH + hsel];
        float as2 = al_s[sc2 * NH + hsel];
        float as3 = al_s[sc3 * NH + hsel];
        ushort4 xv0 = ((const ushort4*)(xpb + (size_t)sc0 * HIDD))[lane];
        ushort4 xv1 = ((const ushort4*)(xpb + (size_t)sc1 * HIDD))[lane];
        ushort4 xv2 = ((const ushort4*)(xpb + (size_t)sc2 * HIDD))[lane];
        ushort4 xv3 = ((const ushort4*)(xpb + (size_t)sc3 * HIDD))[lane];
        float l0 = as0 + adh; l0 = l0 > 0.f ? l0 : NEGS * l0;
        float l1 = as1 + adh; l1 = l1 > 0.f ? l1 : NEGS * l1;
        float l2 = as2 + adh; l2 = l2 > 0.f ? l2 : NEGS * l2;
        float l3 = as3 + adh; l3 = l3 > 0.f ? l3 : NEGS * l3;
        float w0 = __expf(l0), w1 = __expf(l1), w2 = __expf(l2), w3 = __expf(l3);
        den0 += w0; den1 += w1; den2 += w2; den3 += w3;
        acc0.x = fmaf(w0, bf2f(xv0.x), acc0.x); acc0.y = fmaf(w0, bf2f(xv0.y), acc0.y);
        acc0.z = fmaf(w0, bf2f(xv0.z), acc0.z); acc0.w = fmaf(w0, bf2f(xv0.w), acc0.w);
        acc1.x = fmaf(w1, bf2f(xv1.x), acc1.x); acc1.y = fmaf(w1, bf2f(xv1.y), acc1.y);
        acc1.z = fmaf(w1, bf2f(xv1.z), acc1.z); acc1.w = fmaf(w1, bf2f(xv1.w), acc1.w);
        acc2.x = fmaf(w2, bf2f(xv2.x), acc2.x); acc2.y = fmaf(w2, bf2f(xv2.y), acc2.y);
        acc2.z = fmaf(w2, bf2f(xv2.z), acc2.z); acc2.w = fmaf(w2, bf2f(xv2.w), acc2.w);
        acc3.x = fmaf(w3, bf2f(xv3.x), acc3.x); acc3.y = fmaf(w3, bf2f(xv3.y), acc3.y);
        acc3.z = fmaf(w3, bf2f(xv3.z), acc3.z); acc3.w = fmaf(w3, bf2f(xv3.w), acc3.w);
    }
    for (; e < hi; ++e) {
        int sc = col_idx[e];
        float as = al_s[sc * NH + hsel];
        ushort4 xv = ((const ushort4*)(xpb + (size_t)sc * HIDD))[lane];
        float l = as + adh; l = l > 0.f ? l : NEGS * l;
        float wt = __expf(l);
        den0 += wt;
        acc0.x = fmaf(wt, bf2f(xv.x), acc0.x); acc0.y = fmaf(wt, bf2f(xv.y), acc0.y);
        acc0.z = fmaf(wt, bf2f(xv.z), acc0.z); acc0.w = fmaf(wt, bf2f(xv.w), acc0.w);
    }

    float inv = 1.f / ((den0 + den1) + (den2 + den3) + 1e-16f);
    float4 acc;
    acc.x = ((acc0.x + acc1.x) + (acc2.x + acc3.x)) * inv;
    acc.y = ((acc0.y + acc1.y) + (acc2.y + acc3.y)) * inv;
    acc.z = ((acc0.z + acc1.z) + (acc2.z + acc3.z)) * inv;
    acc.w = ((acc0.w + acc1.w) + (acc2.w + acc3.w)) * inv;

    // epilogue: bias + BN(eval) + ReLU
    float4 bi = ((const float4*)bias)[lane];
    float4 gg = ((const float4*)bg)[lane];
    float4 be = ((const float4*)bb)[lane];
    float4 mn = ((const float4*)bm)[lane];
    float4 vr = ((const float4*)bv)[lane];
    float4 val;
    val.x = (acc.x + bi.x - mn.x) * rsqrtf(vr.x + BNEPS) * gg.x + be.x;
    val.y = (acc.y + bi.y - mn.y) * rsqrtf(vr.y + BNEPS) * gg.y + be.y;
    val.z = (acc.z + bi.z - mn.z) * rsqrtf(vr.z + BNEPS) * gg.z + be.z;
    val.w = (acc.w + bi.w - mn.w) * rsqrtf(vr.w + BNEPS) * gg.w + be.w;
    val.x = val.x > 0.f ? val.x : 0.f;
    val.y = val.y > 0.f ? val.y : 0.f;
    val.z = val.z > 0.f ? val.z : 0.f;
    val.w = val.w > 0.f ? val.w : 0.f;
    if (wmask & 1)
        ((float4*)h)[(size_t)node * 64 + lane] = val;
    if (wmask & 2) {
        union { __hip_bfloat16 b[4]; ushort4 u; } cv;
        cv.b[0] = __float2bfloat16(val.x); cv.b[1] = __float2bfloat16(val.y);
        cv.b[2] = __float2bfloat16(val.z); cv.b[3] = __float2bfloat16(val.w);
        ((ushort4*)hb)[(size_t)node * 64 + lane] = cv.u;
    }
}

// ---------- parallel pooling: partial sums per (graph, chunk) ----------
__global__ void k_pool2(const float* __restrict__ h, const int* __restrict__ batch,
                        float* __restrict__ partial) {
    int g = blockIdx.x, i = blockIdx.y, col = threadIdx.x;
    int lo = lower_bound_i(batch, NN, g);
    int hi = lower_bound_i(batch, NN, g + 1);
    int len = hi - lo;
    int a = lo + (int)((long)len * i / PSPLIT);
    int b = lo + (int)((long)len * (i + 1) / PSPLIT);
    float acc = 0.f;
    for (int n = a; n < b; ++n) acc += h[(size_t)n * HIDD + col];
    partial[((size_t)g * PSPLIT + i) * HIDD + col] = acc;
}

// ---------- final: sum partials + BN + FC ----------
__global__ __launch_bounds__(64) void k_final(const float* __restrict__ partial,
                                              const float* __restrict__ lg,
                                              const float* __restrict__ lb,
                                              const float* __restrict__ lm,
                                              const float* __restrict__ lv,
                                              const float* __restrict__ fcW,
                                              const float* __restrict__ fcb,
                                              float* __restrict__ out) {
    __shared__ float ps[HIDD];
    int g = blockIdx.x, j = threadIdx.x;
    for (int k = j; k < HIDD; k += 64) {
        float s = 0.f;
        for (int i = 0; i < PSPLIT; ++i)
            s += partial[((size_t)g * PSPLIT + i) * HIDD + k];
        ps[k] = (s - lm[k]) * rsqrtf(lv[k] + BNEPS) * lg[k] + lb[k];
    }
    __syncthreads();
    float acc = 0.f;
    for (int k = 0; k < HIDD; ++k)
        acc = fmaf(ps[k], fcW[k * LATD + j], acc);
    out[g * LATD + j] = acc + fcb[j];
}

extern "C" void kernel_launch(void* const* d_in, const int* in_sizes, int n_in,
                              void* d_out, int out_size, void* d_ws, size_t ws_size,
                              hipStream_t stream) {
    const float* x     = (const float*)d_in[0];
    const int*   ei    = (const int*)d_in[1];
    const int*   batch = (const int*)d_in[2];
    const float* W0    = (const float*)d_in[3];
    const float* Wr    = (const float*)d_in[4];
    const float* asrc  = (const float*)d_in[5];
    const float* adst  = (const float*)d_in[6];
    const float* bconv = (const float*)d_in[7];
    const float* bng   = (const float*)d_in[8];
    const float* bnb   = (const float*)d_in[9];
    const float* bnm   = (const float*)d_in[10];
    const float* bnv   = (const float*)d_in[11];
    const float* lg    = (const float*)d_in[12];
    const float* lb    = (const float*)d_in[13];
    const float* lm    = (const float*)d_in[14];
    const float* lv    = (const float*)d_in[15];
    const float* fcW   = (const float*)d_in[16];
    const float* fcb   = (const float*)d_in[17];
    float* out = (float*)d_out;

    char* w = (char*)d_ws;
    size_t off = 0;
    auto alloc = [&](size_t bytes) {
        char* p = w + off;
        off += (bytes + 255) / 256 * 256;
        return p;
    };
    float* hbuf  = (float*)alloc((size_t)NN * HIDD * 4);    // layer-2 activations fp32
    float* al_s  = (float*)alloc((size_t)NN * NH * 4);
    float* al_d  = (float*)alloc((size_t)NN * NH * 4);
    float* partial = (float*)alloc((size_t)NG * PSPLIT * HIDD * 4);
    __hip_bfloat16* hbx = (__hip_bfloat16*)alloc((size_t)MPAD * IND * 2);   // bf16 x
    __hip_bfloat16* hb2 = (__hip_bfloat16*)alloc((size_t)MPAD * HIDD * 2);  // bf16 activations
    __hip_bfloat16* xpb = (__hip_bfloat16*)alloc((size_t)MPAD * HIDD * 2);  // bf16 xp
    __hip_bfloat16* Wt  = (__hip_bfloat16*)alloc((size_t)HIDD * HIDD * 2);  // bf16 W^T
    int* deg     = (int*)alloc((size_t)NN * 4);
    int* row_ptr = (int*)alloc((size_t)(NN + 1) * 4);
    int* cursor  = (int*)alloc((size_t)NN * 4);
    int* col_idx = (int*)alloc((size_t)EE * 4);
    int* bsum    = (int*)alloc((size_t)NB * 4);
    int* boff    = (int*)alloc((size_t)NB * 4);

    // ---- CSR build (dst-sorted edges) ----
    hipMemsetAsync(deg, 0, (size_t)NN * sizeof(int), stream);
    hipLaunchKernelGGL(k_hist, dim3((EE + 255) / 256), dim3(256), 0, stream, ei, deg);
    hipLaunchKernelGGL(k_blocksum, dim3(NB), dim3(256), 0, stream, deg, bsum);
    hipLaunchKernelGGL(k_scanbs, dim3(1), dim3(128), 0, stream, bsum, boff, row_ptr);
    hipLaunchKernelGGL(k_scanapply, dim3(NB), dim3(256), 0, stream, deg, boff, row_ptr, cursor);
    hipLaunchKernelGGL(k_csr_scatter, dim3((EE + 255) / 256), dim3(256), 0, stream,
                       ei, cursor, col_idx);

    hipLaunchKernelGGL(k_cast_x, dim3((NN * IND / 4 + 255) / 256), dim3(256), 0, stream, x, hbx);

    for (int layer = 0; layer < 3; ++layer) {
        const float* W = (layer == 0) ? W0 : (Wr + (size_t)(layer - 1) * HIDD * HIDD);
        int K          = (layer == 0) ? IND : HIDD;
        const __hip_bfloat16* Ab = (layer == 0) ? hbx : hb2;
        int wmask      = (layer == 2) ? 1 : 2;   // fp32 h only for last layer; bf16 only before

        hipLaunchKernelGGL(k_cast_wt, dim3(K), dim3(HIDD), 0, stream, W, K, Wt);
        hipLaunchKernelGGL(k_gemm, dim3(MPAD / BM, HIDD / BN), dim3(256), 0, stream,
                           (const short*)Ab, (const short*)Wt, K, xpb);
        hipLaunchKernelGGL(k_att2, dim3((NN + 3) / 4), dim3(256), 0, stream,
                           xpb, asrc + layer * NH * NC, adst + layer * NH * NC, al_s, al_d);
        hipLaunchKernelGGL(k_gat_agg, dim3((NN + 3) / 4), dim3(256), 0, stream,
                           row_ptr, col_idx, al_s, al_d, xpb,
                           bconv + layer * HIDD, bng + layer * HIDD, bnb + layer * HIDD,
                           bnm + layer * HIDD, bnv + layer * HIDD, hbuf, hb2, wmask);
    }

    hipLaunchKernelGGL(k_pool2, dim3(NG, PSPLIT), dim3(HIDD), 0, stream, hbuf, batch, partial);
    hipLaunchKernelGGL(k_final, dim3(NG), dim3(LATD), 0, stream,
                       partial, lg, lb, lm, lv, fcW, fcb, out);
}